// Round 7
// baseline (540.331 us; speedup 1.0000x reference)
//
#include <hip/hip_runtime.h>
#include <cstddef>

typedef __attribute__((ext_vector_type(8))) short short8;
typedef __attribute__((ext_vector_type(4))) float f32x4;

__device__ __forceinline__ float b2f(unsigned short u) {
    union { unsigned int i; float f; } x; x.i = ((unsigned int)u) << 16; return x.f;
}
__device__ __forceinline__ unsigned short f2b(float f) {
    union { float f; unsigned int i; } x; x.f = f;
    unsigned int r = x.i + 0x7FFF + ((x.i >> 16) & 1);
    return (unsigned short)(r >> 16);
}
__device__ __forceinline__ float lrelu(float v) { return v > 0.f ? v : 0.2f * v; }

// async global->LDS, 16B per lane. LDS dest is wave-uniform base + lane*16.
__device__ __forceinline__ void gld_lds16(const unsigned short* g, short* l) {
    __builtin_amdgcn_global_load_lds(
        (const __attribute__((address_space(1))) void*)g,
        (__attribute__((address_space(3))) void*)l, 16, 0, 0);
}

// ---------------- CSR build ----------------

__global__ void count_edges_kernel(const int* __restrict__ ei, int E, int N,
                                   int* __restrict__ cnt) {
    int e = blockIdx.x * blockDim.x + threadIdx.x;
    if (e >= E + N) return;
    int d = (e < E) ? ei[E + e] : (e - E);  // self loops appended
    atomicAdd(&cnt[d], 1);
}

// single block, 1024 threads; also re-zeroes cnt for the scatter cursor.
__global__ void scan_kernel(int* __restrict__ cnt, int* __restrict__ rp, int n) {
    __shared__ int sh[1024];
    int t = threadIdx.x;
    int chunk = (n + 1023) >> 10;
    int beg = t * chunk;
    int end = beg + chunk < n ? beg + chunk : n;
    int local = 0;
    for (int i = beg; i < end; i++) local += cnt[i];
    sh[t] = local;
    __syncthreads();
    for (int off = 1; off < 1024; off <<= 1) {
        int v = (t >= off) ? sh[t - off] : 0;
        __syncthreads();
        sh[t] += v;
        __syncthreads();
    }
    int run = (t == 0) ? 0 : sh[t - 1];
    for (int i = beg; i < end; i++) {
        int c = cnt[i];
        cnt[i] = 0;
        run += c;
        rp[i + 1] = run;
    }
    if (t == 0) rp[0] = 0;
}

__global__ void scatter_edges_kernel(const int* __restrict__ ei, int E, int N,
                                     const int* __restrict__ rp, int* __restrict__ cur,
                                     int* __restrict__ csrc) {
    int e = blockIdx.x * blockDim.x + threadIdx.x;
    if (e >= E + N) return;
    int s, d;
    if (e < E) { s = ei[e]; d = ei[E + e]; } else { s = e - E; d = s; }
    int pos = rp[d] + atomicAdd(&cur[d], 1);
    csrc[pos] = s;
}

// ---------------- dtype prep ----------------

__global__ void f32_to_bf16_pad4_kernel(const float* __restrict__ in,
                                        unsigned short* __restrict__ out,
                                        int rows, int cols, int padRows) {
    int i = blockIdx.x * blockDim.x + threadIdx.x;
    int total = (padRows * cols) >> 2;
    if (i >= total) return;
    int r = (i * 4) / cols;
    ushort4 o;
    if (r < rows) {
        float4 v = *(const float4*)(in + (size_t)i * 4);
        o = make_ushort4(f2b(v.x), f2b(v.y), f2b(v.z), f2b(v.w));
    } else {
        o = make_ushort4(0, 0, 0, 0);
    }
    *(ushort4*)(out + (size_t)i * 4) = o;
}

// All four weight transposes in one launch.
__global__ void transpose_all_kernel(
    const float* __restrict__ W1, const float* __restrict__ W2,
    const float* __restrict__ Wm, const float* __restrict__ Wl,
    unsigned short* __restrict__ W1t, unsigned short* __restrict__ W2t,
    unsigned short* __restrict__ WmlT) {
    int i = blockIdx.x * blockDim.x + threadIdx.x;
    if (i < 65536) {
        int k = i >> 8, n = i & 255;
        W1t[(size_t)n * 256 + k] = f2b(W1[i]);
    } else if (i < 65536 + 131072) {
        int j = i - 65536;
        int k = j >> 9, n = j & 511;
        W2t[(size_t)n * 256 + k] = f2b(W2[j]);
    } else if (i < 65536 + 131072 + 65536) {
        int j = i - 196608;
        int k = j >> 7, n = j & 127;
        WmlT[(size_t)n * 512 + k] = f2b(Wm[j]);
    } else if (i < 65536 + 131072 + 131072) {
        int j = i - 262144;
        int k = j >> 7, n = j & 127;
        WmlT[(size_t)(128 + n) * 512 + k] = f2b(Wl[j]);
    }
}

// ---------------- bf16 MFMA GEMM + fused attention-logit epilogue ----------------
// C[M,Nc] = A[Mp,K] @ Bt[Nc,K]^T; 128x128 tile, BK=32, 256 threads (2x2 waves).
// Staging via global_load_lds width=16 (m97 pattern). Epilogue also computes
// partial al_src/al_dst dots (f32 acc x a-vector columns) and atomicAdds into
// al_s/al_d[row*H + head]; head = col / Chead, a-vectors indexed by flat col
// (split at csplit between lo/hi pointer pairs).

__global__ __launch_bounds__(256) void gemm_bf16_kernel(
    const unsigned short* __restrict__ A, const unsigned short* __restrict__ Bt,
    unsigned short* __restrict__ C, int M, int K, int Nc,
    float* __restrict__ al_s, float* __restrict__ al_d,
    const float* __restrict__ aslo, const float* __restrict__ adlo,
    const float* __restrict__ ashi, const float* __restrict__ adhi,
    int csplit, int Chead, int H) {
    __shared__ short As[128 * 32];
    __shared__ short Bs[128 * 32];
    int tid = threadIdx.x;
    int bm = blockIdx.y * 128;
    int bn = blockIdx.x * 128;
    int wave = tid >> 6, lane = tid & 63;
    int wm = (wave >> 1) * 64, wn = (wave & 1) * 64;
    int lm = lane & 15, lq = lane >> 4;

    f32x4 acc[4][4] = {};

    int c0 = tid, c1 = tid + 256;
    const unsigned short* Ap0 = A + (size_t)(bm + (c0 >> 2)) * K + (c0 & 3) * 8;
    const unsigned short* Ap1 = A + (size_t)(bm + (c1 >> 2)) * K + (c1 & 3) * 8;
    const unsigned short* Bp0 = Bt + (size_t)(bn + (c0 >> 2)) * K + (c0 & 3) * 8;
    const unsigned short* Bp1 = Bt + (size_t)(bn + (c1 >> 2)) * K + (c1 & 3) * 8;
    // wave-uniform LDS bases: chunk range [wave*64, wave*64+64) and +256
    short* as0 = &As[(wave * 64) * 8];
    short* as1 = &As[(wave * 64 + 256) * 8];
    short* bs0 = &Bs[(wave * 64) * 8];
    short* bs1 = &Bs[(wave * 64 + 256) * 8];

    for (int kk = 0; kk < K; kk += 32) {
        __syncthreads();  // all waves done reading previous tile
        gld_lds16(Ap0 + kk, as0);
        gld_lds16(Ap1 + kk, as1);
        gld_lds16(Bp0 + kk, bs0);
        gld_lds16(Bp1 + kk, bs1);
        __syncthreads();  // barrier drains vmcnt -> tile resident
        short8 af[4], bf[4];
#pragma unroll
        for (int t = 0; t < 4; t++) {
            af[t] = *(const short8*)&As[(wm + t * 16 + lm) * 32 + lq * 8];
            bf[t] = *(const short8*)&Bs[(wn + t * 16 + lm) * 32 + lq * 8];
        }
#pragma unroll
        for (int tm = 0; tm < 4; tm++)
#pragma unroll
            for (int tn = 0; tn < 4; tn++)
                acc[tm][tn] = __builtin_amdgcn_mfma_f32_16x16x32_bf16(
                    af[tm], bf[tn], acc[tm][tn], 0, 0, 0);
    }

    // C store (bf16)
#pragma unroll
    for (int tm = 0; tm < 4; tm++) {
#pragma unroll
        for (int r = 0; r < 4; r++) {
            int row = bm + wm + tm * 16 + lq * 4 + r;
            if (row < M) {
#pragma unroll
                for (int tn = 0; tn < 4; tn++) {
                    int col = bn + wn + tn * 16 + lm;
                    C[(size_t)row * Nc + col] = f2b(acc[tm][tn][r]);
                }
            }
        }
    }

    // fused attention-logit partial dots
    float asv[4], adv[4];
#pragma unroll
    for (int tn = 0; tn < 4; tn++) {
        int col = bn + wn + tn * 16 + lm;
        bool hi = col >= csplit;
        int cc = hi ? col - csplit : col;
        asv[tn] = hi ? ashi[cc] : aslo[cc];
        adv[tn] = hi ? adhi[cc] : adlo[cc];
    }
#pragma unroll
    for (int tm = 0; tm < 4; tm++) {
#pragma unroll
        for (int r = 0; r < 4; r++) {
            int row = bm + wm + tm * 16 + lq * 4 + r;
#pragma unroll
            for (int p = 0; p < 2; p++) {   // 32-col groups (always within a head)
                float s1 = acc[tm][2 * p][r] * asv[2 * p]
                         + acc[tm][2 * p + 1][r] * asv[2 * p + 1];
                float s2 = acc[tm][2 * p][r] * adv[2 * p]
                         + acc[tm][2 * p + 1][r] * adv[2 * p + 1];
#pragma unroll
                for (int off = 8; off >= 1; off >>= 1) {
                    s1 += __shfl_xor(s1, off);
                    s2 += __shfl_xor(s2, off);
                }
                if (lm == 0 && row < M) {
                    int head = (bn + wn + p * 32) / Chead;
                    atomicAdd(&al_s[(size_t)row * H + head], s1);
                    atomicAdd(&al_d[(size_t)row * H + head], s2);
                }
            }
        }
    }
}

// ---------------- fused per-node softmax + aggregate, 4 nodes/block ----------------
// 4 waves per block, each wave owns one dst node (wave-local LDS sections, no
// cross-wave sync). Lane-per-edge softmax via butterfly shuffles; alpha parked
// in LDS; gather-aggregate V channels/lane.
// MODE 0: concat + bias + ReLU, bf16 out. MODE 1: 8 heads x 32ch -> head-mean
// over groups 0-3 / 4-7 + bias, f32 out1/out2.

template <int H4, int V, int MODE>
__global__ __launch_bounds__(256) void gat_fused_kernel(
    const int* __restrict__ rp, const int* __restrict__ csrc,
    const float* __restrict__ al_s, const float* __restrict__ al_d,
    const unsigned short* __restrict__ h,
    const float* __restrict__ bias1, const float* __restrict__ bias2,
    void* __restrict__ out1v, void* __restrict__ out2v, int HC, int C, int N) {
    const int H = 4 * H4;
    __shared__ int lds_src[4][64];
    __shared__ float lds_alpha[4][64 * 4 * H4];
    __shared__ float shred[4][256];
    int wv = threadIdx.x >> 6;
    int lane = threadIdx.x & 63;
    int n = blockIdx.x * 4 + wv;
    if (n >= N) return;
    int beg = rp[n], end = rp[n + 1];
    int deg = end - beg;

    float ad[H];
#pragma unroll
    for (int g = 0; g < H4; g++)
        *(float4*)&ad[g * 4] = *(const float4*)(al_d + (size_t)n * H + g * 4);

    int ch = lane * V;
    int hh = ch / C;
    float acc[V];
#pragma unroll
    for (int j = 0; j < V; j++) acc[j] = 0.f;

    if (deg <= 64) {
        bool act = lane < deg;
        int s = act ? csrc[beg + lane] : 0;
        float v[H], m[H], ex[H], sum[H];
#pragma unroll
        for (int g = 0; g < H4; g++) {
            float4 as = *(const float4*)(al_s + (size_t)s * H + g * 4);
            v[g * 4 + 0] = lrelu(as.x + ad[g * 4 + 0]);
            v[g * 4 + 1] = lrelu(as.y + ad[g * 4 + 1]);
            v[g * 4 + 2] = lrelu(as.z + ad[g * 4 + 2]);
            v[g * 4 + 3] = lrelu(as.w + ad[g * 4 + 3]);
        }
#pragma unroll
        for (int j = 0; j < H; j++) m[j] = act ? v[j] : -3.402823466e38f;
#pragma unroll
        for (int off = 32; off >= 1; off >>= 1)
#pragma unroll
            for (int j = 0; j < H; j++) m[j] = fmaxf(m[j], __shfl_xor(m[j], off));
#pragma unroll
        for (int j = 0; j < H; j++) {
            ex[j] = act ? __expf(v[j] - m[j]) : 0.f;
            sum[j] = ex[j];
        }
#pragma unroll
        for (int off = 32; off >= 1; off >>= 1)
#pragma unroll
            for (int j = 0; j < H; j++) sum[j] += __shfl_xor(sum[j], off);
        if (act) {
            lds_src[wv][lane] = s;
#pragma unroll
            for (int g = 0; g < H4; g++) {
                float4 o;
                o.x = ex[g * 4 + 0] / (sum[g * 4 + 0] + 1e-16f);
                o.y = ex[g * 4 + 1] / (sum[g * 4 + 1] + 1e-16f);
                o.z = ex[g * 4 + 2] / (sum[g * 4 + 2] + 1e-16f);
                o.w = ex[g * 4 + 3] / (sum[g * 4 + 3] + 1e-16f);
                *(float4*)&lds_alpha[wv][lane * H + g * 4] = o;
            }
        }
        // wave-local LDS write->read: lockstep wave + compiler lgkmcnt ordering
        int t = 0;
        for (; t + 4 <= deg; t += 4) {
#pragma unroll
            for (int u = 0; u < 4; u++) {
                int s2 = lds_src[wv][t + u];
                float a = lds_alpha[wv][(t + u) * H + hh];
                const unsigned short* p = h + (size_t)s2 * HC + ch;
                if constexpr (V == 8) {
                    short8 uv = *(const short8*)p;
#pragma unroll
                    for (int j = 0; j < 8; j++) acc[j] += a * b2f((unsigned short)uv[j]);
                } else {
                    ushort4 u4 = *(const ushort4*)p;
                    acc[0] += a * b2f(u4.x); acc[1] += a * b2f(u4.y);
                    acc[2] += a * b2f(u4.z); acc[3] += a * b2f(u4.w);
                }
            }
        }
        for (; t < deg; t++) {
            int s2 = lds_src[wv][t];
            float a = lds_alpha[wv][t * H + hh];
            const unsigned short* p = h + (size_t)s2 * HC + ch;
            if constexpr (V == 8) {
                short8 uv = *(const short8*)p;
#pragma unroll
                for (int j = 0; j < 8; j++) acc[j] += a * b2f((unsigned short)uv[j]);
            } else {
                ushort4 u4 = *(const ushort4*)p;
                acc[0] += a * b2f(u4.x); acc[1] += a * b2f(u4.y);
                acc[2] += a * b2f(u4.z); acc[3] += a * b2f(u4.w);
            }
        }
    } else {
        // general path (deg > 64): strided stats with recompute, chunked agg
        float m[H], sum[H];
#pragma unroll
        for (int j = 0; j < H; j++) m[j] = -3.402823466e38f;
        for (int e = beg + lane; e < end; e += 64) {
            int s = csrc[e];
#pragma unroll
            for (int g = 0; g < H4; g++) {
                float4 as = *(const float4*)(al_s + (size_t)s * H + g * 4);
                m[g * 4 + 0] = fmaxf(m[g * 4 + 0], lrelu(as.x + ad[g * 4 + 0]));
                m[g * 4 + 1] = fmaxf(m[g * 4 + 1], lrelu(as.y + ad[g * 4 + 1]));
                m[g * 4 + 2] = fmaxf(m[g * 4 + 2], lrelu(as.z + ad[g * 4 + 2]));
                m[g * 4 + 3] = fmaxf(m[g * 4 + 3], lrelu(as.w + ad[g * 4 + 3]));
            }
        }
#pragma unroll
        for (int off = 32; off >= 1; off >>= 1)
#pragma unroll
            for (int j = 0; j < H; j++) m[j] = fmaxf(m[j], __shfl_xor(m[j], off));
#pragma unroll
        for (int j = 0; j < H; j++) sum[j] = 0.f;
        for (int e = beg + lane; e < end; e += 64) {
            int s = csrc[e];
#pragma unroll
            for (int g = 0; g < H4; g++) {
                float4 as = *(const float4*)(al_s + (size_t)s * H + g * 4);
                sum[g * 4 + 0] += __expf(lrelu(as.x + ad[g * 4 + 0]) - m[g * 4 + 0]);
                sum[g * 4 + 1] += __expf(lrelu(as.y + ad[g * 4 + 1]) - m[g * 4 + 1]);
                sum[g * 4 + 2] += __expf(lrelu(as.z + ad[g * 4 + 2]) - m[g * 4 + 2]);
                sum[g * 4 + 3] += __expf(lrelu(as.w + ad[g * 4 + 3]) - m[g * 4 + 3]);
            }
        }
#pragma unroll
        for (int off = 32; off >= 1; off >>= 1)
#pragma unroll
            for (int j = 0; j < H; j++) sum[j] += __shfl_xor(sum[j], off);
        float r[H];
#pragma unroll
        for (int j = 0; j < H; j++) r[j] = 1.0f / (sum[j] + 1e-16f);
        for (int base = beg; base < end; base += 64) {
            int cn = end - base < 64 ? end - base : 64;
            if (lane < cn) {
                int s = csrc[base + lane];
                lds_src[wv][lane] = s;
#pragma unroll
                for (int g = 0; g < H4; g++) {
                    float4 as = *(const float4*)(al_s + (size_t)s * H + g * 4);
                    float4 o;
                    o.x = __expf(lrelu(as.x + ad[g * 4 + 0]) - m[g * 4 + 0]) * r[g * 4 + 0];
                    o.y = __expf(lrelu(as.y + ad[g * 4 + 1]) - m[g * 4 + 1]) * r[g * 4 + 1];
                    o.z = __expf(lrelu(as.z + ad[g * 4 + 2]) - m[g * 4 + 2]) * r[g * 4 + 2];
                    o.w = __expf(lrelu(as.w + ad[g * 4 + 3]) - m[g * 4 + 3]) * r[g * 4 + 3];
                    *(float4*)&lds_alpha[wv][lane * H + g * 4] = o;
                }
            }
            for (int t = 0; t < cn; t++) {
                int s2 = lds_src[wv][t];
                float a = lds_alpha[wv][t * H + hh];
                const unsigned short* p = h + (size_t)s2 * HC + ch;
                if constexpr (V == 8) {
                    short8 uv = *(const short8*)p;
#pragma unroll
                    for (int j = 0; j < 8; j++) acc[j] += a * b2f((unsigned short)uv[j]);
                } else {
                    ushort4 u4 = *(const ushort4*)p;
                    acc[0] += a * b2f(u4.x); acc[1] += a * b2f(u4.y);
                    acc[2] += a * b2f(u4.z); acc[3] += a * b2f(u4.w);
                }
            }
        }
    }

    if constexpr (MODE == 0) {
        unsigned short* out = (unsigned short*)out1v;
        if constexpr (V == 8) {
            short8 o;
#pragma unroll
            for (int j = 0; j < 8; j++)
                o[j] = (short)f2b(fmaxf(acc[j] + bias1[ch + j], 0.f));
            *(short8*)(out + (size_t)n * HC + ch) = o;
        } else {
            ushort4 o;
            o.x = f2b(fmaxf(acc[0] + bias1[ch + 0], 0.f));
            o.y = f2b(fmaxf(acc[1] + bias1[ch + 1], 0.f));
            o.z = f2b(fmaxf(acc[2] + bias1[ch + 2], 0.f));
            o.w = f2b(fmaxf(acc[3] + bias1[ch + 3], 0.f));
            *(ushort4*)(out + (size_t)n * HC + ch) = o;
        }
    } else {
        // MODE 1: HC=256, V=4, 8 heads x 32ch -> mean over heads 0-3 / 4-7
        *(float4*)&shred[wv][ch] = make_float4(acc[0], acc[1], acc[2], acc[3]);
        if (lane < 32) {
            float v1 = (shred[wv][lane] + shred[wv][lane + 32] + shred[wv][lane + 64]
                        + shred[wv][lane + 96]) * 0.25f + bias1[lane];
            float v2 = (shred[wv][lane + 128] + shred[wv][lane + 160]
                        + shred[wv][lane + 192] + shred[wv][lane + 224]) * 0.25f
                       + bias2[lane];
            ((float*)out1v)[(size_t)n * 32 + lane] = v1;
            ((float*)out2v)[(size_t)n * 32 + lane] = v2;
        }
    }
}

// ---------------- orchestration ----------------

extern "C" void kernel_launch(void* const* d_in, const int* in_sizes, int n_in,
                              void* d_out, int out_size, void* d_ws, size_t ws_size,
                              hipStream_t stream) {
    (void)n_in; (void)out_size; (void)ws_size;
    const float* x   = (const float*)d_in[0];
    const int*   ei  = (const int*)d_in[1];
    const float* W1  = (const float*)d_in[2];
    const float* as1 = (const float*)d_in[3];
    const float* ad1 = (const float*)d_in[4];
    const float* b1  = (const float*)d_in[5];
    const float* W2  = (const float*)d_in[6];
    const float* as2 = (const float*)d_in[7];
    const float* ad2 = (const float*)d_in[8];
    const float* b2  = (const float*)d_in[9];
    const float* Wm  = (const float*)d_in[10];
    const float* a_sm = (const float*)d_in[11];
    const float* a_dm = (const float*)d_in[12];
    const float* bm  = (const float*)d_in[13];
    const float* Wl  = (const float*)d_in[14];
    const float* a_sl = (const float*)d_in[15];
    const float* a_dl = (const float*)d_in[16];
    const float* bl  = (const float*)d_in[17];
    float* outp = (float*)d_out;

    const int N  = in_sizes[0] / 256;   // 30000
    const int E  = in_sizes[1] / 2;     // 480000
    const int ET = E + N;               // with self loops
    const int gM = (N + 127) / 128;     // 235
    const int Mp = gM * 128;            // 30080

    auto align_up = [](size_t v) { return (v + 255) & ~(size_t)255; };
    char* w = (char*)d_ws;
    int* row_ptr = (int*)w;  w += align_up((size_t)(N + 1) * 4);
    int* cnt     = (int*)w;  w += align_up((size_t)N * 4);
    int* csrc    = (int*)w;  w += align_up((size_t)ET * 4);
    float* al_s  = (float*)w; w += align_up((size_t)N * 8 * 4);
    float* al_d  = (float*)w; w += align_up((size_t)N * 8 * 4);
    unsigned short* xb   = (unsigned short*)w; w += align_up((size_t)Mp * 256 * 2);
    unsigned short* W1t  = (unsigned short*)w; w += align_up((size_t)256 * 256 * 2);
    unsigned short* W2t  = (unsigned short*)w; w += align_up((size_t)512 * 256 * 2);
    unsigned short* WmlT = (unsigned short*)w; w += align_up((size_t)256 * 512 * 2);
    unsigned short* bufH = (unsigned short*)w; w += align_up((size_t)Mp * 512 * 2);
    unsigned short* bufO = (unsigned short*)w; w += align_up((size_t)Mp * 512 * 2);

    const size_t alBytes = (size_t)N * 8 * 4 * 2;  // al_s + al_d (contiguous)

    // ---- CSR build ----
    int gzE = (ET + 255) / 256;
    hipMemsetAsync(cnt, 0, (size_t)N * 4, stream);
    count_edges_kernel<<<gzE, 256, 0, stream>>>(ei, E, N, cnt);
    scan_kernel<<<1, 1024, 0, stream>>>(cnt, row_ptr, N);   // re-zeroes cnt
    scatter_edges_kernel<<<gzE, 256, 0, stream>>>(ei, E, N, row_ptr, cnt, csrc);

    // ---- dtype prep ----
    f32_to_bf16_pad4_kernel<<<((Mp * 256 / 4) + 255) / 256, 256, 0, stream>>>(
        x, xb, N, 256, Mp);
    transpose_all_kernel<<<(393216 + 255) / 256, 256, 0, stream>>>(
        W1, W2, Wm, Wl, W1t, W2t, WmlT);

    int gF = (N + 3) / 4;

    // ---- Layer 1: GAT(256 -> 4x64, concat) + ReLU ----
    hipMemsetAsync(al_s, 0, alBytes, stream);
    gemm_bf16_kernel<<<dim3(2, gM), 256, 0, stream>>>(
        xb, W1t, bufH, N, 256, 256, al_s, al_d, as1, ad1, as1, ad1, 256, 64, 4);
    gat_fused_kernel<1, 4, 0><<<gF, 256, 0, stream>>>(
        row_ptr, csrc, al_s, al_d, bufH, b1, nullptr, bufO, nullptr, 256, 64, N);

    // ---- Layer 2: GAT(256 -> 4x128, concat) + ReLU ----
    hipMemsetAsync(al_s, 0, alBytes, stream);
    gemm_bf16_kernel<<<dim3(4, gM), 256, 0, stream>>>(
        bufO, W2t, bufH, N, 256, 512, al_s, al_d, as2, ad2, as2, ad2, 512, 128, 4);
    gat_fused_kernel<1, 8, 0><<<gF, 256, 0, stream>>>(
        row_ptr, csrc, al_s, al_d, bufH, b2, nullptr, bufO, nullptr, 512, 128, N);

    // ---- Layers 3+4 batched: GAT(512 -> 8x32, mean per 4-head group) ----
    hipMemsetAsync(al_s, 0, alBytes, stream);
    gemm_bf16_kernel<<<dim3(2, gM), 256, 0, stream>>>(
        bufO, WmlT, bufH, N, 512, 256, al_s, al_d, a_sm, a_dm, a_sl, a_dl, 128, 32, 8);
    gat_fused_kernel<2, 4, 1><<<gF, 256, 0, stream>>>(
        row_ptr, csrc, al_s, al_d, bufH, bm, bl, outp, outp + (size_t)N * 32, 256, 32, N);
}

// Round 8
// 525.428 us; speedup vs baseline: 1.0284x; 1.0284x over previous
//
#include <hip/hip_runtime.h>
#include <cstddef>

typedef __attribute__((ext_vector_type(8))) short short8;
typedef __attribute__((ext_vector_type(4))) float f32x4;

__device__ __forceinline__ float b2f(unsigned short u) {
    union { unsigned int i; float f; } x; x.i = ((unsigned int)u) << 16; return x.f;
}
__device__ __forceinline__ unsigned short f2b(float f) {
    union { float f; unsigned int i; } x; x.f = f;
    unsigned int r = x.i + 0x7FFF + ((x.i >> 16) & 1);
    return (unsigned short)(r >> 16);
}
__device__ __forceinline__ float lrelu(float v) { return v > 0.f ? v : 0.2f * v; }

// ---------------- CSR build ----------------

__global__ void count_edges_kernel(const int* __restrict__ ei, int E, int N,
                                   int* __restrict__ cnt) {
    int e = blockIdx.x * blockDim.x + threadIdx.x;
    if (e >= E + N) return;
    int d = (e < E) ? ei[E + e] : (e - E);  // self loops appended
    atomicAdd(&cnt[d], 1);
}

// single block, 1024 threads; also re-zeroes cnt for the scatter cursor.
__global__ void scan_kernel(int* __restrict__ cnt, int* __restrict__ rp, int n) {
    __shared__ int sh[1024];
    int t = threadIdx.x;
    int chunk = (n + 1023) >> 10;
    int beg = t * chunk;
    int end = beg + chunk < n ? beg + chunk : n;
    int local = 0;
    for (int i = beg; i < end; i++) local += cnt[i];
    sh[t] = local;
    __syncthreads();
    for (int off = 1; off < 1024; off <<= 1) {
        int v = (t >= off) ? sh[t - off] : 0;
        __syncthreads();
        sh[t] += v;
        __syncthreads();
    }
    int run = (t == 0) ? 0 : sh[t - 1];
    for (int i = beg; i < end; i++) {
        int c = cnt[i];
        cnt[i] = 0;
        run += c;
        rp[i + 1] = run;
    }
    if (t == 0) rp[0] = 0;
}

__global__ void scatter_edges_kernel(const int* __restrict__ ei, int E, int N,
                                     const int* __restrict__ rp, int* __restrict__ cur,
                                     int* __restrict__ csrc) {
    int e = blockIdx.x * blockDim.x + threadIdx.x;
    if (e >= E + N) return;
    int s, d;
    if (e < E) { s = ei[e]; d = ei[E + e]; } else { s = e - E; d = s; }
    int pos = rp[d] + atomicAdd(&cur[d], 1);
    csrc[pos] = s;
}

// ---------------- dtype prep ----------------

__global__ void f32_to_bf16_pad4_kernel(const float* __restrict__ in,
                                        unsigned short* __restrict__ out,
                                        int rows, int cols, int padRows) {
    int i = blockIdx.x * blockDim.x + threadIdx.x;
    int total = (padRows * cols) >> 2;
    if (i >= total) return;
    int r = (i * 4) / cols;
    ushort4 o;
    if (r < rows) {
        float4 v = *(const float4*)(in + (size_t)i * 4);
        o = make_ushort4(f2b(v.x), f2b(v.y), f2b(v.z), f2b(v.w));
    } else {
        o = make_ushort4(0, 0, 0, 0);
    }
    *(ushort4*)(out + (size_t)i * 4) = o;
}

// All four weight transposes in one launch.
__global__ void transpose_all_kernel(
    const float* __restrict__ W1, const float* __restrict__ W2,
    const float* __restrict__ Wm, const float* __restrict__ Wl,
    unsigned short* __restrict__ W1t, unsigned short* __restrict__ W2t,
    unsigned short* __restrict__ WmlT) {
    int i = blockIdx.x * blockDim.x + threadIdx.x;
    if (i < 65536) {
        int k = i >> 8, n = i & 255;
        W1t[(size_t)n * 256 + k] = f2b(W1[i]);
    } else if (i < 65536 + 131072) {
        int j = i - 65536;
        int k = j >> 9, n = j & 511;
        W2t[(size_t)n * 256 + k] = f2b(W2[j]);
    } else if (i < 65536 + 131072 + 65536) {
        int j = i - 196608;
        int k = j >> 7, n = j & 127;
        WmlT[(size_t)n * 512 + k] = f2b(Wm[j]);
    } else if (i < 65536 + 131072 + 131072) {
        int j = i - 262144;
        int k = j >> 7, n = j & 127;
        WmlT[(size_t)(128 + n) * 512 + k] = f2b(Wl[j]);
    }
}

// ---------------- barrier-free bf16 MFMA GEMM ----------------
// C[M,Nc] = A[Mp,K] @ Bt[Nc,K]^T. 128x128 tile, 256 threads (2x2 waves of
// 64x64). NO LDS, NO barriers: each lane loads its MFMA fragments directly
// from global (B <= 512 KB lives in L2/LLC; A-line footprint identical to a
// staged load). Double-buffered one K-iter ahead so HBM/L2 latency overlaps
// the 16 MFMAs; waves pipeline independently.

__global__ __launch_bounds__(256) void gemm_bf16_kernel(
    const unsigned short* __restrict__ A, const unsigned short* __restrict__ Bt,
    unsigned short* __restrict__ C, int M, int K, int Nc) {
    int tid = threadIdx.x;
    int bm = blockIdx.y * 128;
    int bn = blockIdx.x * 128;
    int wave = tid >> 6, lane = tid & 63;
    int wm = (wave >> 1) * 64, wn = (wave & 1) * 64;
    int lm = lane & 15, lq = lane >> 4;

    const unsigned short* Ap[4];
    const unsigned short* Bp[4];
#pragma unroll
    for (int t = 0; t < 4; t++) {
        Ap[t] = A + (size_t)(bm + wm + t * 16 + lm) * K + lq * 8;
        Bp[t] = Bt + (size_t)(bn + wn + t * 16 + lm) * K + lq * 8;
    }

    f32x4 acc[4][4] = {};
    short8 a0[4], b0[4], a1[4], b1[4];
#pragma unroll
    for (int t = 0; t < 4; t++) {
        a0[t] = *(const short8*)(Ap[t]);
        b0[t] = *(const short8*)(Bp[t]);
    }
    for (int kk = 0; kk < K; kk += 32) {
        if (kk + 32 < K) {
#pragma unroll
            for (int t = 0; t < 4; t++) {
                a1[t] = *(const short8*)(Ap[t] + kk + 32);
                b1[t] = *(const short8*)(Bp[t] + kk + 32);
            }
        }
#pragma unroll
        for (int tm = 0; tm < 4; tm++)
#pragma unroll
            for (int tn = 0; tn < 4; tn++)
                acc[tm][tn] = __builtin_amdgcn_mfma_f32_16x16x32_bf16(
                    a0[tm], b0[tn], acc[tm][tn], 0, 0, 0);
#pragma unroll
        for (int t = 0; t < 4; t++) { a0[t] = a1[t]; b0[t] = b1[t]; }
    }

#pragma unroll
    for (int tm = 0; tm < 4; tm++) {
#pragma unroll
        for (int r = 0; r < 4; r++) {
            int row = bm + wm + tm * 16 + lq * 4 + r;
            if (row < M) {
#pragma unroll
                for (int tn = 0; tn < 4; tn++) {
                    int col = bn + wn + tn * 16 + lm;
                    C[(size_t)row * Nc + col] = f2b(acc[tm][tn][r]);
                }
            }
        }
    }
}

// ---------------- attention logits (H heads, hi pointers for heads 4..7) ----------------

__global__ __launch_bounds__(256) void al_kernel(
    const unsigned short* __restrict__ h,
    const float* __restrict__ aslo, const float* __restrict__ adlo,
    const float* __restrict__ ashi, const float* __restrict__ adhi,
    float* __restrict__ al_s, float* __restrict__ al_d,
    int NHtot, int HC, int C, int H) {
    int lane = threadIdx.x & 63;
    int wv = blockIdx.x * 4 + (threadIdx.x >> 6);
    if (C >= 64) {
        if (wv >= NHtot) return;
        int n = wv / H, hh = wv % H;
        const float* as_ = (hh < 4) ? (aslo + hh * C) : (ashi + (hh - 4) * C);
        const float* ad_ = (hh < 4) ? (adlo + hh * C) : (adhi + (hh - 4) * C);
        const unsigned short* row = h + (size_t)n * HC + hh * C;
        float s1 = 0.f, s2 = 0.f;
        for (int c = lane; c < C; c += 64) {
            float v = b2f(row[c]);
            s1 += v * as_[c];
            s2 += v * ad_[c];
        }
#pragma unroll
        for (int off = 32; off > 0; off >>= 1) {
            s1 += __shfl_down(s1, off);
            s2 += __shfl_down(s2, off);
        }
        if (lane == 0) { al_s[wv] = s1; al_d[wv] = s2; }
    } else {  // C == 32: two (n,head) pairs per wave
        int wid = wv * 2 + (lane >> 5);
        int widc = wid < NHtot ? wid : NHtot - 1;
        int n = widc / H, hh = widc % H;
        const float* as_ = (hh < 4) ? (aslo + hh * C) : (ashi + (hh - 4) * C);
        const float* ad_ = (hh < 4) ? (adlo + hh * C) : (adhi + (hh - 4) * C);
        int c = lane & 31;
        float v = b2f(h[(size_t)n * HC + hh * C + c]);
        float s1 = v * as_[c], s2 = v * ad_[c];
#pragma unroll
        for (int off = 16; off > 0; off >>= 1) {
            s1 += __shfl_down(s1, off);
            s2 += __shfl_down(s2, off);
        }
        if ((lane & 31) == 0 && wid < NHtot) { al_s[wid] = s1; al_d[wid] = s2; }
    }
}

// ---------------- fused per-node softmax + aggregate, 4 nodes/block ----------------
// 4 waves per block, each wave owns one dst node (wave-local LDS sections, no
// cross-wave sync). Lane-per-edge softmax via butterfly shuffles; alpha parked
// in LDS; gather-aggregate V channels/lane.
// MODE 0: concat + bias + ReLU, bf16 out. MODE 1: 8 heads x 32ch -> head-mean
// over groups 0-3 / 4-7 + bias, f32 out1/out2.

template <int H4, int V, int MODE>
__global__ __launch_bounds__(256) void gat_fused_kernel(
    const int* __restrict__ rp, const int* __restrict__ csrc,
    const float* __restrict__ al_s, const float* __restrict__ al_d,
    const unsigned short* __restrict__ h,
    const float* __restrict__ bias1, const float* __restrict__ bias2,
    void* __restrict__ out1v, void* __restrict__ out2v, int HC, int C, int N) {
    const int H = 4 * H4;
    __shared__ int lds_src[4][64];
    __shared__ float lds_alpha[4][64 * 4 * H4];
    __shared__ float shred[4][256];
    int wv = threadIdx.x >> 6;
    int lane = threadIdx.x & 63;
    int n = blockIdx.x * 4 + wv;
    if (n >= N) return;
    int beg = rp[n], end = rp[n + 1];
    int deg = end - beg;

    float ad[H];
#pragma unroll
    for (int g = 0; g < H4; g++)
        *(float4*)&ad[g * 4] = *(const float4*)(al_d + (size_t)n * H + g * 4);

    int ch = lane * V;
    int hh = ch / C;
    float acc[V];
#pragma unroll
    for (int j = 0; j < V; j++) acc[j] = 0.f;

    if (deg <= 64) {
        bool act = lane < deg;
        int s = act ? csrc[beg + lane] : 0;
        float v[H], m[H], ex[H], sum[H];
#pragma unroll
        for (int g = 0; g < H4; g++) {
            float4 as = *(const float4*)(al_s + (size_t)s * H + g * 4);
            v[g * 4 + 0] = lrelu(as.x + ad[g * 4 + 0]);
            v[g * 4 + 1] = lrelu(as.y + ad[g * 4 + 1]);
            v[g * 4 + 2] = lrelu(as.z + ad[g * 4 + 2]);
            v[g * 4 + 3] = lrelu(as.w + ad[g * 4 + 3]);
        }
#pragma unroll
        for (int j = 0; j < H; j++) m[j] = act ? v[j] : -3.402823466e38f;
#pragma unroll
        for (int off = 32; off >= 1; off >>= 1)
#pragma unroll
            for (int j = 0; j < H; j++) m[j] = fmaxf(m[j], __shfl_xor(m[j], off));
#pragma unroll
        for (int j = 0; j < H; j++) {
            ex[j] = act ? __expf(v[j] - m[j]) : 0.f;
            sum[j] = ex[j];
        }
#pragma unroll
        for (int off = 32; off >= 1; off >>= 1)
#pragma unroll
            for (int j = 0; j < H; j++) sum[j] += __shfl_xor(sum[j], off);
        if (act) {
            lds_src[wv][lane] = s;
#pragma unroll
            for (int g = 0; g < H4; g++) {
                float4 o;
                o.x = ex[g * 4 + 0] / (sum[g * 4 + 0] + 1e-16f);
                o.y = ex[g * 4 + 1] / (sum[g * 4 + 1] + 1e-16f);
                o.z = ex[g * 4 + 2] / (sum[g * 4 + 2] + 1e-16f);
                o.w = ex[g * 4 + 3] / (sum[g * 4 + 3] + 1e-16f);
                *(float4*)&lds_alpha[wv][lane * H + g * 4] = o;
            }
        }
        // wave-local LDS write->read: lockstep wave + compiler lgkmcnt ordering
        int t = 0;
        for (; t + 4 <= deg; t += 4) {
#pragma unroll
            for (int u = 0; u < 4; u++) {
                int s2 = lds_src[wv][t + u];
                float a = lds_alpha[wv][(t + u) * H + hh];
                const unsigned short* p = h + (size_t)s2 * HC + ch;
                if constexpr (V == 8) {
                    short8 uv = *(const short8*)p;
#pragma unroll
                    for (int j = 0; j < 8; j++) acc[j] += a * b2f((unsigned short)uv[j]);
                } else {
                    ushort4 u4 = *(const ushort4*)p;
                    acc[0] += a * b2f(u4.x); acc[1] += a * b2f(u4.y);
                    acc[2] += a * b2f(u4.z); acc[3] += a * b2f(u4.w);
                }
            }
        }
        for (; t < deg; t++) {
            int s2 = lds_src[wv][t];
            float a = lds_alpha[wv][t * H + hh];
            const unsigned short* p = h + (size_t)s2 * HC + ch;
            if constexpr (V == 8) {
                short8 uv = *(const short8*)p;
#pragma unroll
                for (int j = 0; j < 8; j++) acc[j] += a * b2f((unsigned short)uv[j]);
            } else {
                ushort4 u4 = *(const ushort4*)p;
                acc[0] += a * b2f(u4.x); acc[1] += a * b2f(u4.y);
                acc[2] += a * b2f(u4.z); acc[3] += a * b2f(u4.w);
            }
        }
    } else {
        // general path (deg > 64): strided stats with recompute, chunked agg
        float m[H], sum[H];
#pragma unroll
        for (int j = 0; j < H; j++) m[j] = -3.402823466e38f;
        for (int e = beg + lane; e < end; e += 64) {
            int s = csrc[e];
#pragma unroll
            for (int g = 0; g < H4; g++) {
                float4 as = *(const float4*)(al_s + (size_t)s * H + g * 4);
                m[g * 4 + 0] = fmaxf(m[g * 4 + 0], lrelu(as.x + ad[g * 4 + 0]));
                m[g * 4 + 1] = fmaxf(m[g * 4 + 1], lrelu(as.y + ad[g * 4 + 1]));
                m[g * 4 + 2] = fmaxf(m[g * 4 + 2], lrelu(as.z + ad[g * 4 + 2]));
                m[g * 4 + 3] = fmaxf(m[g * 4 + 3], lrelu(as.w + ad[g * 4 + 3]));
            }
        }
#pragma unroll
        for (int off = 32; off >= 1; off >>= 1)
#pragma unroll
            for (int j = 0; j < H; j++) m[j] = fmaxf(m[j], __shfl_xor(m[j], off));
#pragma unroll
        for (int j = 0; j < H; j++) sum[j] = 0.f;
        for (int e = beg + lane; e < end; e += 64) {
            int s = csrc[e];
#pragma unroll
            for (int g = 0; g < H4; g++) {
                float4 as = *(const float4*)(al_s + (size_t)s * H + g * 4);
                sum[g * 4 + 0] += __expf(lrelu(as.x + ad[g * 4 + 0]) - m[g * 4 + 0]);
                sum[g * 4 + 1] += __expf(lrelu(as.y + ad[g * 4 + 1]) - m[g * 4 + 1]);
                sum[g * 4 + 2] += __expf(lrelu(as.z + ad[g * 4 + 2]) - m[g * 4 + 2]);
                sum[g * 4 + 3] += __expf(lrelu(as.w + ad[g * 4 + 3]) - m[g * 4 + 3]);
            }
        }
#pragma unroll
        for (int off = 32; off >= 1; off >>= 1)
#pragma unroll
            for (int j = 0; j < H; j++) sum[j] += __shfl_xor(sum[j], off);
        float r[H];
#pragma unroll
        for (int j = 0; j < H; j++) r[j] = 1.0f / (sum[j] + 1e-16f);
        for (int base = beg; base < end; base += 64) {
            int cn = end - base < 64 ? end - base : 64;
            if (lane < cn) {
                int s = csrc[base + lane];
                lds_src[wv][lane] = s;
#pragma unroll
                for (int g = 0; g < H4; g++) {
                    float4 as = *(const float4*)(al_s + (size_t)s * H + g * 4);
                    float4 o;
                    o.x = __expf(lrelu(as.x + ad[g * 4 + 0]) - m[g * 4 + 0]) * r[g * 4 + 0];
                    o.y = __expf(lrelu(as.y + ad[g * 4 + 1]) - m[g * 4 + 1]) * r[g * 4 + 1];
                    o.z = __expf(lrelu(as.z + ad[g * 4 + 2]) - m[g * 4 + 2]) * r[g * 4 + 2];
                    o.w = __expf(lrelu(as.w + ad[g * 4 + 3]) - m[g * 4 + 3]) * r[g * 4 + 3];
                    *(float4*)&lds_alpha[wv][lane * H + g * 4] = o;
                }
            }
            for (int t = 0; t < cn; t++) {
                int s2 = lds_src[wv][t];
                float a = lds_alpha[wv][t * H + hh];
                const unsigned short* p = h + (size_t)s2 * HC + ch;
                if constexpr (V == 8) {
                    short8 uv = *(const short8*)p;
#pragma unroll
                    for (int j = 0; j < 8; j++) acc[j] += a * b2f((unsigned short)uv[j]);
                } else {
                    ushort4 u4 = *(const ushort4*)p;
                    acc[0] += a * b2f(u4.x); acc[1] += a * b2f(u4.y);
                    acc[2] += a * b2f(u4.z); acc[3] += a * b2f(u4.w);
                }
            }
        }
    }

    if constexpr (MODE == 0) {
        unsigned short* out = (unsigned short*)out1v;
        if constexpr (V == 8) {
            short8 o;
#pragma unroll
            for (int j = 0; j < 8; j++)
                o[j] = (short)f2b(fmaxf(acc[j] + bias1[ch + j], 0.f));
            *(short8*)(out + (size_t)n * HC + ch) = o;
        } else {
            ushort4 o;
            o.x = f2b(fmaxf(acc[0] + bias1[ch + 0], 0.f));
            o.y = f2b(fmaxf(acc[1] + bias1[ch + 1], 0.f));
            o.z = f2b(fmaxf(acc[2] + bias1[ch + 2], 0.f));
            o.w = f2b(fmaxf(acc[3] + bias1[ch + 3], 0.f));
            *(ushort4*)(out + (size_t)n * HC + ch) = o;
        }
    } else {
        // MODE 1: HC=256, V=4, 8 heads x 32ch -> mean over heads 0-3 / 4-7
        *(float4*)&shred[wv][ch] = make_float4(acc[0], acc[1], acc[2], acc[3]);
        if (lane < 32) {
            float v1 = (shred[wv][lane] + shred[wv][lane + 32] + shred[wv][lane + 64]
                        + shred[wv][lane + 96]) * 0.25f + bias1[lane];
            float v2 = (shred[wv][lane + 128] + shred[wv][lane + 160]
                        + shred[wv][lane + 192] + shred[wv][lane + 224]) * 0.25f
                       + bias2[lane];
            ((float*)out1v)[(size_t)n * 32 + lane] = v1;
            ((float*)out2v)[(size_t)n * 32 + lane] = v2;
        }
    }
}

// ---------------- orchestration ----------------

extern "C" void kernel_launch(void* const* d_in, const int* in_sizes, int n_in,
                              void* d_out, int out_size, void* d_ws, size_t ws_size,
                              hipStream_t stream) {
    (void)n_in; (void)out_size; (void)ws_size;
    const float* x   = (const float*)d_in[0];
    const int*   ei  = (const int*)d_in[1];
    const float* W1  = (const float*)d_in[2];
    const float* as1 = (const float*)d_in[3];
    const float* ad1 = (const float*)d_in[4];
    const float* b1  = (const float*)d_in[5];
    const float* W2  = (const float*)d_in[6];
    const float* as2 = (const float*)d_in[7];
    const float* ad2 = (const float*)d_in[8];
    const float* b2  = (const float*)d_in[9];
    const float* Wm  = (const float*)d_in[10];
    const float* a_sm = (const float*)d_in[11];
    const float* a_dm = (const float*)d_in[12];
    const float* bm  = (const float*)d_in[13];
    const float* Wl  = (const float*)d_in[14];
    const float* a_sl = (const float*)d_in[15];
    const float* a_dl = (const float*)d_in[16];
    const float* bl  = (const float*)d_in[17];
    float* outp = (float*)d_out;

    const int N  = in_sizes[0] / 256;   // 30000
    const int E  = in_sizes[1] / 2;     // 480000
    const int ET = E + N;               // with self loops
    const int gM = (N + 127) / 128;     // 235
    const int Mp = gM * 128;            // 30080

    auto align_up = [](size_t v) { return (v + 255) & ~(size_t)255; };
    char* w = (char*)d_ws;
    int* row_ptr = (int*)w;  w += align_up((size_t)(N + 1) * 4);
    int* cnt     = (int*)w;  w += align_up((size_t)N * 4);
    int* csrc    = (int*)w;  w += align_up((size_t)ET * 4);
    float* al_s  = (float*)w; w += align_up((size_t)N * 8 * 4);
    float* al_d  = (float*)w; w += align_up((size_t)N * 8 * 4);
    unsigned short* xb   = (unsigned short*)w; w += align_up((size_t)Mp * 256 * 2);
    unsigned short* W1t  = (unsigned short*)w; w += align_up((size_t)256 * 256 * 2);
    unsigned short* W2t  = (unsigned short*)w; w += align_up((size_t)512 * 256 * 2);
    unsigned short* WmlT = (unsigned short*)w; w += align_up((size_t)256 * 512 * 2);
    unsigned short* bufH = (unsigned short*)w; w += align_up((size_t)Mp * 512 * 2);
    unsigned short* bufO = (unsigned short*)w; w += align_up((size_t)Mp * 512 * 2);

    // ---- CSR build ----
    int gzE = (ET + 255) / 256;
    hipMemsetAsync(cnt, 0, (size_t)N * 4, stream);
    count_edges_kernel<<<gzE, 256, 0, stream>>>(ei, E, N, cnt);
    scan_kernel<<<1, 1024, 0, stream>>>(cnt, row_ptr, N);   // re-zeroes cnt
    scatter_edges_kernel<<<gzE, 256, 0, stream>>>(ei, E, N, row_ptr, cnt, csrc);

    // ---- dtype prep ----
    f32_to_bf16_pad4_kernel<<<((Mp * 256 / 4) + 255) / 256, 256, 0, stream>>>(
        x, xb, N, 256, Mp);
    transpose_all_kernel<<<(393216 + 255) / 256, 256, 0, stream>>>(
        W1, W2, Wm, Wl, W1t, W2t, WmlT);

    int gF = (N + 3) / 4;

    // ---- Layer 1: GAT(256 -> 4x64, concat) + ReLU ----
    gemm_bf16_kernel<<<dim3(2, gM), 256, 0, stream>>>(xb, W1t, bufH, N, 256, 256);
    al_kernel<<<(N * 4 + 3) / 4, 256, 0, stream>>>(bufH, as1, ad1, as1, ad1,
                                                   al_s, al_d, N * 4, 256, 64, 4);
    gat_fused_kernel<1, 4, 0><<<gF, 256, 0, stream>>>(
        row_ptr, csrc, al_s, al_d, bufH, b1, nullptr, bufO, nullptr, 256, 64, N);

    // ---- Layer 2: GAT(256 -> 4x128, concat) + ReLU ----
    gemm_bf16_kernel<<<dim3(4, gM), 256, 0, stream>>>(bufO, W2t, bufH, N, 256, 512);
    al_kernel<<<(N * 4 + 3) / 4, 256, 0, stream>>>(bufH, as2, ad2, as2, ad2,
                                                   al_s, al_d, N * 4, 512, 128, 4);
    gat_fused_kernel<1, 8, 0><<<gF, 256, 0, stream>>>(
        row_ptr, csrc, al_s, al_d, bufH, b2, nullptr, bufO, nullptr, 512, 128, N);

    // ---- Layers 3+4 batched: GAT(512 -> 8x32, mean per 4-head group) ----
    gemm_bf16_kernel<<<dim3(2, gM), 256, 0, stream>>>(bufO, WmlT, bufH, N, 512, 256);
    al_kernel<<<(N * 8 + 7) / 8, 256, 0, stream>>>(bufH, a_sm, a_dm, a_sl, a_dl,
                                                   al_s, al_d, N * 8, 256, 32, 8);
    gat_fused_kernel<2, 4, 1><<<gF, 256, 0, stream>>>(
        row_ptr, csrc, al_s, al_d, bufH, bm, bl, outp, outp + (size_t)N * 32, 256, 32, N);
}

// Round 9
// 458.092 us; speedup vs baseline: 1.1795x; 1.1470x over previous
//
#include <hip/hip_runtime.h>
#include <cstddef>

typedef __attribute__((ext_vector_type(8))) short short8;
typedef __attribute__((ext_vector_type(4))) float f32x4;

__device__ __forceinline__ float b2f(unsigned short u) {
    union { unsigned int i; float f; } x; x.i = ((unsigned int)u) << 16; return x.f;
}
__device__ __forceinline__ unsigned short f2b(float f) {
    union { float f; unsigned int i; } x; x.f = f;
    unsigned int r = x.i + 0x7FFF + ((x.i >> 16) & 1);
    return (unsigned short)(r >> 16);
}
__device__ __forceinline__ float lrelu(float v) { return v > 0.f ? v : 0.2f * v; }

// ---------------- CSR build ----------------

__global__ void count_edges_kernel(const int* __restrict__ ei, int E, int N,
                                   int* __restrict__ cnt) {
    int e = blockIdx.x * blockDim.x + threadIdx.x;
    if (e >= E + N) return;
    int d = (e < E) ? ei[E + e] : (e - E);  // self loops appended
    atomicAdd(&cnt[d], 1);
}

// single block, 1024 threads; also re-zeroes cnt for the scatter cursor.
__global__ void scan_kernel(int* __restrict__ cnt, int* __restrict__ rp, int n) {
    __shared__ int sh[1024];
    int t = threadIdx.x;
    int chunk = (n + 1023) >> 10;
    int beg = t * chunk;
    int end = beg + chunk < n ? beg + chunk : n;
    int local = 0;
    for (int i = beg; i < end; i++) local += cnt[i];
    sh[t] = local;
    __syncthreads();
    for (int off = 1; off < 1024; off <<= 1) {
        int v = (t >= off) ? sh[t - off] : 0;
        __syncthreads();
        sh[t] += v;
        __syncthreads();
    }
    int run = (t == 0) ? 0 : sh[t - 1];
    for (int i = beg; i < end; i++) {
        int c = cnt[i];
        cnt[i] = 0;
        run += c;
        rp[i + 1] = run;
    }
    if (t == 0) rp[0] = 0;
}

__global__ void scatter_edges_kernel(const int* __restrict__ ei, int E, int N,
                                     const int* __restrict__ rp, int* __restrict__ cur,
                                     int* __restrict__ csrc) {
    int e = blockIdx.x * blockDim.x + threadIdx.x;
    if (e >= E + N) return;
    int s, d;
    if (e < E) { s = ei[e]; d = ei[E + e]; } else { s = e - E; d = s; }
    int pos = rp[d] + atomicAdd(&cur[d], 1);
    csrc[pos] = s;
}

// ---------------- dtype prep ----------------

__global__ void f32_to_bf16_pad4_kernel(const float* __restrict__ in,
                                        unsigned short* __restrict__ out,
                                        int rows, int cols, int padRows) {
    int i = blockIdx.x * blockDim.x + threadIdx.x;
    int total = (padRows * cols) >> 2;
    if (i >= total) return;
    int r = (i * 4) / cols;
    ushort4 o;
    if (r < rows) {
        float4 v = *(const float4*)(in + (size_t)i * 4);
        o = make_ushort4(f2b(v.x), f2b(v.y), f2b(v.z), f2b(v.w));
    } else {
        o = make_ushort4(0, 0, 0, 0);
    }
    *(ushort4*)(out + (size_t)i * 4) = o;
}

// All four weight transposes in one launch.
__global__ void transpose_all_kernel(
    const float* __restrict__ W1, const float* __restrict__ W2,
    const float* __restrict__ Wm, const float* __restrict__ Wl,
    unsigned short* __restrict__ W1t, unsigned short* __restrict__ W2t,
    unsigned short* __restrict__ WmlT) {
    int i = blockIdx.x * blockDim.x + threadIdx.x;
    if (i < 65536) {
        int k = i >> 8, n = i & 255;
        W1t[(size_t)n * 256 + k] = f2b(W1[i]);
    } else if (i < 65536 + 131072) {
        int j = i - 65536;
        int k = j >> 9, n = j & 511;
        W2t[(size_t)n * 256 + k] = f2b(W2[j]);
    } else if (i < 65536 + 131072 + 65536) {
        int j = i - 196608;
        int k = j >> 7, n = j & 127;
        WmlT[(size_t)n * 512 + k] = f2b(Wm[j]);
    } else if (i < 65536 + 131072 + 131072) {
        int j = i - 262144;
        int k = j >> 7, n = j & 127;
        WmlT[(size_t)(128 + n) * 512 + k] = f2b(Wl[j]);
    }
}

// ---------------- bf16 MFMA GEMM + no-atomic attention-logit epilogue ----------------
// C[M,Nc] = A[Mp,K] @ Bt[Nc,K]^T; 128x128 tile, BK=32, 256 threads (2x2 waves),
// register staging -> LDS (loads issued before barrier overlap prev MFMAs).
// Epilogue: cols [bn,bn+128) contain COMPLETE heads (Chead | 128), and each
// (row, 32-col-group) partial dot is produced by exactly one wave -> 16-lane
// shfl reduce -> LDS scatter -> row-threads sum groups -> direct stores of
// al_s/al_d (no atomics). a-vectors indexed by flat col, lo/hi split at csplit.

__global__ __launch_bounds__(256) void gemm_bf16_kernel(
    const unsigned short* __restrict__ A, const unsigned short* __restrict__ Bt,
    unsigned short* __restrict__ C, int M, int K, int Nc,
    float* __restrict__ al_s, float* __restrict__ al_d,
    const float* __restrict__ aslo, const float* __restrict__ adlo,
    const float* __restrict__ ashi, const float* __restrict__ adhi,
    int csplit, int Chead, int H) {
    __shared__ short As[128 * 32];
    __shared__ short Bs[128 * 32];
    __shared__ float salS[128][4];
    __shared__ float salD[128][4];
    int tid = threadIdx.x;
    int bm = blockIdx.y * 128;
    int bn = blockIdx.x * 128;
    int wave = tid >> 6, lane = tid & 63;
    int wm = (wave >> 1) * 64, wn = (wave & 1) * 64;
    int lm = lane & 15, lq = lane >> 4;

    f32x4 acc[4][4] = {};

    int c0 = tid, c1 = tid + 256;
    const unsigned short* Ap0 = A + (size_t)(bm + (c0 >> 2)) * K + (c0 & 3) * 8;
    const unsigned short* Ap1 = A + (size_t)(bm + (c1 >> 2)) * K + (c1 & 3) * 8;
    const unsigned short* Bp0 = Bt + (size_t)(bn + (c0 >> 2)) * K + (c0 & 3) * 8;
    const unsigned short* Bp1 = Bt + (size_t)(bn + (c1 >> 2)) * K + (c1 & 3) * 8;

    for (int kk = 0; kk < K; kk += 32) {
        short8 a0 = *(const short8*)(Ap0 + kk);
        short8 a1 = *(const short8*)(Ap1 + kk);
        short8 b0 = *(const short8*)(Bp0 + kk);
        short8 b1 = *(const short8*)(Bp1 + kk);
        __syncthreads();
        *(short8*)&As[c0 * 8] = a0;
        *(short8*)&As[c1 * 8] = a1;
        *(short8*)&Bs[c0 * 8] = b0;
        *(short8*)&Bs[c1 * 8] = b1;
        __syncthreads();
        short8 af[4], bf[4];
#pragma unroll
        for (int t = 0; t < 4; t++) {
            af[t] = *(const short8*)&As[(wm + t * 16 + lm) * 32 + lq * 8];
            bf[t] = *(const short8*)&Bs[(wn + t * 16 + lm) * 32 + lq * 8];
        }
#pragma unroll
        for (int tm = 0; tm < 4; tm++)
#pragma unroll
            for (int tn = 0; tn < 4; tn++)
                acc[tm][tn] = __builtin_amdgcn_mfma_f32_16x16x32_bf16(
                    af[tm], bf[tn], acc[tm][tn], 0, 0, 0);
    }

    // C store (bf16)
#pragma unroll
    for (int tm = 0; tm < 4; tm++) {
#pragma unroll
        for (int r = 0; r < 4; r++) {
            int row = bm + wm + tm * 16 + lq * 4 + r;
            if (row < M) {
#pragma unroll
                for (int tn = 0; tn < 4; tn++) {
                    int col = bn + wn + tn * 16 + lm;
                    C[(size_t)row * Nc + col] = f2b(acc[tm][tn][r]);
                }
            }
        }
    }

    // attention-logit partial dots -> LDS (each (row, 32-col group) owned by
    // exactly one wave; no races)
    float asv[4], adv[4];
#pragma unroll
    for (int tn = 0; tn < 4; tn++) {
        int col = bn + wn + tn * 16 + lm;
        bool hi = col >= csplit;
        int cc = hi ? col - csplit : col;
        asv[tn] = hi ? ashi[cc] : aslo[cc];
        adv[tn] = hi ? adhi[cc] : adlo[cc];
    }
    int gb = wn >> 5;  // 0 or 2
#pragma unroll
    for (int tm = 0; tm < 4; tm++) {
#pragma unroll
        for (int r = 0; r < 4; r++) {
#pragma unroll
            for (int p = 0; p < 2; p++) {
                float s1 = acc[tm][2 * p][r] * asv[2 * p]
                         + acc[tm][2 * p + 1][r] * asv[2 * p + 1];
                float s2 = acc[tm][2 * p][r] * adv[2 * p]
                         + acc[tm][2 * p + 1][r] * adv[2 * p + 1];
#pragma unroll
                for (int off = 8; off >= 1; off >>= 1) {
                    s1 += __shfl_xor(s1, off);
                    s2 += __shfl_xor(s2, off);
                }
                if (lm == 0) {
                    int rl = wm + tm * 16 + lq * 4 + r;
                    salS[rl][gb + p] = s1;
                    salD[rl][gb + p] = s2;
                }
            }
        }
    }
    __syncthreads();
    if (tid < 128) {
        int row = bm + tid;
        if (row < M) {
            int hb = bn / Chead;       // first head in this col-block
            int HB = 128 / Chead;      // heads per col-block (1, 2, or 4)
            int GH = Chead >> 5;       // 32-col groups per head
            for (int i = 0; i < HB; i++) {
                float ss = 0.f, sd = 0.f;
                for (int j = 0; j < GH; j++) {
                    ss += salS[tid][i * GH + j];
                    sd += salD[tid][i * GH + j];
                }
                al_s[(size_t)row * H + hb + i] = ss;
                al_d[(size_t)row * H + hb + i] = sd;
            }
        }
    }
}

// ---------------- fused per-node softmax + aggregate, 4 nodes/block ----------------
// 4 waves per block, each wave owns one dst node (wave-local LDS sections, no
// cross-wave sync). Lane-per-edge softmax via butterfly shuffles; alpha parked
// in LDS; gather-aggregate V channels/lane.
// MODE 0: concat + bias + ReLU, bf16 out. MODE 1: 8 heads x 32ch -> head-mean
// over groups 0-3 / 4-7 + bias, f32 out1/out2.

template <int H4, int V, int MODE>
__global__ __launch_bounds__(256) void gat_fused_kernel(
    const int* __restrict__ rp, const int* __restrict__ csrc,
    const float* __restrict__ al_s, const float* __restrict__ al_d,
    const unsigned short* __restrict__ h,
    const float* __restrict__ bias1, const float* __restrict__ bias2,
    void* __restrict__ out1v, void* __restrict__ out2v, int HC, int C, int N) {
    const int H = 4 * H4;
    __shared__ int lds_src[4][64];
    __shared__ float lds_alpha[4][64 * 4 * H4];
    __shared__ float shred[4][256];
    int wv = threadIdx.x >> 6;
    int lane = threadIdx.x & 63;
    int n = blockIdx.x * 4 + wv;
    if (n >= N) return;
    int beg = rp[n], end = rp[n + 1];
    int deg = end - beg;

    float ad[H];
#pragma unroll
    for (int g = 0; g < H4; g++)
        *(float4*)&ad[g * 4] = *(const float4*)(al_d + (size_t)n * H + g * 4);

    int ch = lane * V;
    int hh = ch / C;
    float acc[V];
#pragma unroll
    for (int j = 0; j < V; j++) acc[j] = 0.f;

    if (deg <= 64) {
        bool act = lane < deg;
        int s = act ? csrc[beg + lane] : 0;
        float v[H], m[H], ex[H], sum[H];
#pragma unroll
        for (int g = 0; g < H4; g++) {
            float4 as = *(const float4*)(al_s + (size_t)s * H + g * 4);
            v[g * 4 + 0] = lrelu(as.x + ad[g * 4 + 0]);
            v[g * 4 + 1] = lrelu(as.y + ad[g * 4 + 1]);
            v[g * 4 + 2] = lrelu(as.z + ad[g * 4 + 2]);
            v[g * 4 + 3] = lrelu(as.w + ad[g * 4 + 3]);
        }
#pragma unroll
        for (int j = 0; j < H; j++) m[j] = act ? v[j] : -3.402823466e38f;
#pragma unroll
        for (int off = 32; off >= 1; off >>= 1)
#pragma unroll
            for (int j = 0; j < H; j++) m[j] = fmaxf(m[j], __shfl_xor(m[j], off));
#pragma unroll
        for (int j = 0; j < H; j++) {
            ex[j] = act ? __expf(v[j] - m[j]) : 0.f;
            sum[j] = ex[j];
        }
#pragma unroll
        for (int off = 32; off >= 1; off >>= 1)
#pragma unroll
            for (int j = 0; j < H; j++) sum[j] += __shfl_xor(sum[j], off);
        if (act) {
            lds_src[wv][lane] = s;
#pragma unroll
            for (int g = 0; g < H4; g++) {
                float4 o;
                o.x = ex[g * 4 + 0] / (sum[g * 4 + 0] + 1e-16f);
                o.y = ex[g * 4 + 1] / (sum[g * 4 + 1] + 1e-16f);
                o.z = ex[g * 4 + 2] / (sum[g * 4 + 2] + 1e-16f);
                o.w = ex[g * 4 + 3] / (sum[g * 4 + 3] + 1e-16f);
                *(float4*)&lds_alpha[wv][lane * H + g * 4] = o;
            }
        }
        // wave-local LDS write->read: lockstep wave + compiler lgkmcnt ordering
        int t = 0;
        for (; t + 4 <= deg; t += 4) {
#pragma unroll
            for (int u = 0; u < 4; u++) {
                int s2 = lds_src[wv][t + u];
                float a = lds_alpha[wv][(t + u) * H + hh];
                const unsigned short* p = h + (size_t)s2 * HC + ch;
                if constexpr (V == 8) {
                    short8 uv = *(const short8*)p;
#pragma unroll
                    for (int j = 0; j < 8; j++) acc[j] += a * b2f((unsigned short)uv[j]);
                } else {
                    ushort4 u4 = *(const ushort4*)p;
                    acc[0] += a * b2f(u4.x); acc[1] += a * b2f(u4.y);
                    acc[2] += a * b2f(u4.z); acc[3] += a * b2f(u4.w);
                }
            }
        }
        for (; t < deg; t++) {
            int s2 = lds_src[wv][t];
            float a = lds_alpha[wv][t * H + hh];
            const unsigned short* p = h + (size_t)s2 * HC + ch;
            if constexpr (V == 8) {
                short8 uv = *(const short8*)p;
#pragma unroll
                for (int j = 0; j < 8; j++) acc[j] += a * b2f((unsigned short)uv[j]);
            } else {
                ushort4 u4 = *(const ushort4*)p;
                acc[0] += a * b2f(u4.x); acc[1] += a * b2f(u4.y);
                acc[2] += a * b2f(u4.z); acc[3] += a * b2f(u4.w);
            }
        }
    } else {
        // general path (deg > 64): strided stats with recompute, chunked agg
        float m[H], sum[H];
#pragma unroll
        for (int j = 0; j < H; j++) m[j] = -3.402823466e38f;
        for (int e = beg + lane; e < end; e += 64) {
            int s = csrc[e];
#pragma unroll
            for (int g = 0; g < H4; g++) {
                float4 as = *(const float4*)(al_s + (size_t)s * H + g * 4);
                m[g * 4 + 0] = fmaxf(m[g * 4 + 0], lrelu(as.x + ad[g * 4 + 0]));
                m[g * 4 + 1] = fmaxf(m[g * 4 + 1], lrelu(as.y + ad[g * 4 + 1]));
                m[g * 4 + 2] = fmaxf(m[g * 4 + 2], lrelu(as.z + ad[g * 4 + 2]));
                m[g * 4 + 3] = fmaxf(m[g * 4 + 3], lrelu(as.w + ad[g * 4 + 3]));
            }
        }
#pragma unroll
        for (int off = 32; off >= 1; off >>= 1)
#pragma unroll
            for (int j = 0; j < H; j++) m[j] = fmaxf(m[j], __shfl_xor(m[j], off));
#pragma unroll
        for (int j = 0; j < H; j++) sum[j] = 0.f;
        for (int e = beg + lane; e < end; e += 64) {
            int s = csrc[e];
#pragma unroll
            for (int g = 0; g < H4; g++) {
                float4 as = *(const float4*)(al_s + (size_t)s * H + g * 4);
                sum[g * 4 + 0] += __expf(lrelu(as.x + ad[g * 4 + 0]) - m[g * 4 + 0]);
                sum[g * 4 + 1] += __expf(lrelu(as.y + ad[g * 4 + 1]) - m[g * 4 + 1]);
                sum[g * 4 + 2] += __expf(lrelu(as.z + ad[g * 4 + 2]) - m[g * 4 + 2]);
                sum[g * 4 + 3] += __expf(lrelu(as.w + ad[g * 4 + 3]) - m[g * 4 + 3]);
            }
        }
#pragma unroll
        for (int off = 32; off >= 1; off >>= 1)
#pragma unroll
            for (int j = 0; j < H; j++) sum[j] += __shfl_xor(sum[j], off);
        float r[H];
#pragma unroll
        for (int j = 0; j < H; j++) r[j] = 1.0f / (sum[j] + 1e-16f);
        for (int base = beg; base < end; base += 64) {
            int cn = end - base < 64 ? end - base : 64;
            if (lane < cn) {
                int s = csrc[base + lane];
                lds_src[wv][lane] = s;
#pragma unroll
                for (int g = 0; g < H4; g++) {
                    float4 as = *(const float4*)(al_s + (size_t)s * H + g * 4);
                    float4 o;
                    o.x = __expf(lrelu(as.x + ad[g * 4 + 0]) - m[g * 4 + 0]) * r[g * 4 + 0];
                    o.y = __expf(lrelu(as.y + ad[g * 4 + 1]) - m[g * 4 + 1]) * r[g * 4 + 1];
                    o.z = __expf(lrelu(as.z + ad[g * 4 + 2]) - m[g * 4 + 2]) * r[g * 4 + 2];
                    o.w = __expf(lrelu(as.w + ad[g * 4 + 3]) - m[g * 4 + 3]) * r[g * 4 + 3];
                    *(float4*)&lds_alpha[wv][lane * H + g * 4] = o;
                }
            }
            for (int t = 0; t < cn; t++) {
                int s2 = lds_src[wv][t];
                float a = lds_alpha[wv][t * H + hh];
                const unsigned short* p = h + (size_t)s2 * HC + ch;
                if constexpr (V == 8) {
                    short8 uv = *(const short8*)p;
#pragma unroll
                    for (int j = 0; j < 8; j++) acc[j] += a * b2f((unsigned short)uv[j]);
                } else {
                    ushort4 u4 = *(const ushort4*)p;
                    acc[0] += a * b2f(u4.x); acc[1] += a * b2f(u4.y);
                    acc[2] += a * b2f(u4.z); acc[3] += a * b2f(u4.w);
                }
            }
        }
    }

    if constexpr (MODE == 0) {
        unsigned short* out = (unsigned short*)out1v;
        if constexpr (V == 8) {
            short8 o;
#pragma unroll
            for (int j = 0; j < 8; j++)
                o[j] = (short)f2b(fmaxf(acc[j] + bias1[ch + j], 0.f));
            *(short8*)(out + (size_t)n * HC + ch) = o;
        } else {
            ushort4 o;
            o.x = f2b(fmaxf(acc[0] + bias1[ch + 0], 0.f));
            o.y = f2b(fmaxf(acc[1] + bias1[ch + 1], 0.f));
            o.z = f2b(fmaxf(acc[2] + bias1[ch + 2], 0.f));
            o.w = f2b(fmaxf(acc[3] + bias1[ch + 3], 0.f));
            *(ushort4*)(out + (size_t)n * HC + ch) = o;
        }
    } else {
        // MODE 1: HC=256, V=4, 8 heads x 32ch -> mean over heads 0-3 / 4-7
        *(float4*)&shred[wv][ch] = make_float4(acc[0], acc[1], acc[2], acc[3]);
        if (lane < 32) {
            float v1 = (shred[wv][lane] + shred[wv][lane + 32] + shred[wv][lane + 64]
                        + shred[wv][lane + 96]) * 0.25f + bias1[lane];
            float v2 = (shred[wv][lane + 128] + shred[wv][lane + 160]
                        + shred[wv][lane + 192] + shred[wv][lane + 224]) * 0.25f
                       + bias2[lane];
            ((float*)out1v)[(size_t)n * 32 + lane] = v1;
            ((float*)out2v)[(size_t)n * 32 + lane] = v2;
        }
    }
}

// ---------------- orchestration ----------------

extern "C" void kernel_launch(void* const* d_in, const int* in_sizes, int n_in,
                              void* d_out, int out_size, void* d_ws, size_t ws_size,
                              hipStream_t stream) {
    (void)n_in; (void)out_size; (void)ws_size;
    const float* x   = (const float*)d_in[0];
    const int*   ei  = (const int*)d_in[1];
    const float* W1  = (const float*)d_in[2];
    const float* as1 = (const float*)d_in[3];
    const float* ad1 = (const float*)d_in[4];
    const float* b1  = (const float*)d_in[5];
    const float* W2  = (const float*)d_in[6];
    const float* as2 = (const float*)d_in[7];
    const float* ad2 = (const float*)d_in[8];
    const float* b2  = (const float*)d_in[9];
    const float* Wm  = (const float*)d_in[10];
    const float* a_sm = (const float*)d_in[11];
    const float* a_dm = (const float*)d_in[12];
    const float* bm  = (const float*)d_in[13];
    const float* Wl  = (const float*)d_in[14];
    const float* a_sl = (const float*)d_in[15];
    const float* a_dl = (const float*)d_in[16];
    const float* bl  = (const float*)d_in[17];
    float* outp = (float*)d_out;

    const int N  = in_sizes[0] / 256;   // 30000
    const int E  = in_sizes[1] / 2;     // 480000
    const int ET = E + N;               // with self loops
    const int gM = (N + 127) / 128;     // 235
    const int Mp = gM * 128;            // 30080

    auto align_up = [](size_t v) { return (v + 255) & ~(size_t)255; };
    char* w = (char*)d_ws;
    int* row_ptr = (int*)w;  w += align_up((size_t)(N + 1) * 4);
    int* cnt     = (int*)w;  w += align_up((size_t)N * 4);
    int* csrc    = (int*)w;  w += align_up((size_t)ET * 4);
    float* al_s  = (float*)w; w += align_up((size_t)N * 8 * 4);
    float* al_d  = (float*)w; w += align_up((size_t)N * 8 * 4);
    unsigned short* xb   = (unsigned short*)w; w += align_up((size_t)Mp * 256 * 2);
    unsigned short* W1t  = (unsigned short*)w; w += align_up((size_t)256 * 256 * 2);
    unsigned short* W2t  = (unsigned short*)w; w += align_up((size_t)512 * 256 * 2);
    unsigned short* WmlT = (unsigned short*)w; w += align_up((size_t)256 * 512 * 2);
    unsigned short* bufH = (unsigned short*)w; w += align_up((size_t)Mp * 512 * 2);
    unsigned short* bufO = (unsigned short*)w; w += align_up((size_t)Mp * 512 * 2);

    // ---- CSR build ----
    int gzE = (ET + 255) / 256;
    hipMemsetAsync(cnt, 0, (size_t)N * 4, stream);
    count_edges_kernel<<<gzE, 256, 0, stream>>>(ei, E, N, cnt);
    scan_kernel<<<1, 1024, 0, stream>>>(cnt, row_ptr, N);   // re-zeroes cnt
    scatter_edges_kernel<<<gzE, 256, 0, stream>>>(ei, E, N, row_ptr, cnt, csrc);

    // ---- dtype prep ----
    f32_to_bf16_pad4_kernel<<<((Mp * 256 / 4) + 255) / 256, 256, 0, stream>>>(
        x, xb, N, 256, Mp);
    transpose_all_kernel<<<(393216 + 255) / 256, 256, 0, stream>>>(
        W1, W2, Wm, Wl, W1t, W2t, WmlT);

    int gF = (N + 3) / 4;

    // ---- Layer 1: GAT(256 -> 4x64, concat) + ReLU ----
    gemm_bf16_kernel<<<dim3(2, gM), 256, 0, stream>>>(
        xb, W1t, bufH, N, 256, 256, al_s, al_d, as1, ad1, as1, ad1, 256, 64, 4);
    gat_fused_kernel<1, 4, 0><<<gF, 256, 0, stream>>>(
        row_ptr, csrc, al_s, al_d, bufH, b1, nullptr, bufO, nullptr, 256, 64, N);

    // ---- Layer 2: GAT(256 -> 4x128, concat) + ReLU ----
    gemm_bf16_kernel<<<dim3(4, gM), 256, 0, stream>>>(
        bufO, W2t, bufH, N, 256, 512, al_s, al_d, as2, ad2, as2, ad2, 512, 128, 4);
    gat_fused_kernel<1, 8, 0><<<gF, 256, 0, stream>>>(
        row_ptr, csrc, al_s, al_d, bufH, b2, nullptr, bufO, nullptr, 512, 128, N);

    // ---- Layers 3+4 batched: GAT(512 -> 8x32, mean per 4-head group) ----
    gemm_bf16_kernel<<<dim3(2, gM), 256, 0, stream>>>(
        bufO, WmlT, bufH, N, 512, 256, al_s, al_d, a_sm, a_dm, a_sl, a_dl, 128, 32, 8);
    gat_fused_kernel<2, 4, 1><<<gF, 256, 0, stream>>>(
        row_ptr, csrc, al_s, al_d, bufH, bm, bl, outp, outp + (size_t)N * 32, 256, 32, N);
}

// Round 10
// 450.971 us; speedup vs baseline: 1.1982x; 1.0158x over previous
//
#include <hip/hip_runtime.h>
#include <cstddef>

typedef __attribute__((ext_vector_type(8))) short short8;
typedef __attribute__((ext_vector_type(4))) float f32x4;
typedef __attribute__((ext_vector_type(8))) _Float16 half8;
typedef __attribute__((ext_vector_type(4))) _Float16 half4;

__device__ __forceinline__ unsigned short f2h(float f) {
    union { _Float16 h; unsigned short u; } x; x.h = (_Float16)f; return x.u;
}
__device__ __forceinline__ float h2f(unsigned short u) {
    union { unsigned short u; _Float16 h; } x; x.u = u; return (float)x.h;
}
__device__ __forceinline__ float lrelu(float v) { return v > 0.f ? v : 0.2f * v; }

// ---------------- CSR build ----------------

__global__ void count_edges_kernel(const int* __restrict__ ei, int E, int N,
                                   int* __restrict__ cnt) {
    int e = blockIdx.x * blockDim.x + threadIdx.x;
    if (e >= E + N) return;
    int d = (e < E) ? ei[E + e] : (e - E);  // self loops appended
    atomicAdd(&cnt[d], 1);
}

// single block, 1024 threads; also re-zeroes cnt for the scatter cursor.
__global__ void scan_kernel(int* __restrict__ cnt, int* __restrict__ rp, int n) {
    __shared__ int sh[1024];
    int t = threadIdx.x;
    int chunk = (n + 1023) >> 10;
    int beg = t * chunk;
    int end = beg + chunk < n ? beg + chunk : n;
    int local = 0;
    for (int i = beg; i < end; i++) local += cnt[i];
    sh[t] = local;
    __syncthreads();
    for (int off = 1; off < 1024; off <<= 1) {
        int v = (t >= off) ? sh[t - off] : 0;
        __syncthreads();
        sh[t] += v;
        __syncthreads();
    }
    int run = (t == 0) ? 0 : sh[t - 1];
    for (int i = beg; i < end; i++) {
        int c = cnt[i];
        cnt[i] = 0;
        run += c;
        rp[i + 1] = run;
    }
    if (t == 0) rp[0] = 0;
}

__global__ void scatter_edges_kernel(const int* __restrict__ ei, int E, int N,
                                     const int* __restrict__ rp, int* __restrict__ cur,
                                     int* __restrict__ csrc) {
    int e = blockIdx.x * blockDim.x + threadIdx.x;
    if (e >= E + N) return;
    int s, d;
    if (e < E) { s = ei[e]; d = ei[E + e]; } else { s = e - E; d = s; }
    int pos = rp[d] + atomicAdd(&cur[d], 1);
    csrc[pos] = s;
}

// ---------------- dtype prep ----------------

__global__ void f32_to_f16_pad4_kernel(const float* __restrict__ in,
                                       unsigned short* __restrict__ out,
                                       int rows, int cols, int padRows) {
    int i = blockIdx.x * blockDim.x + threadIdx.x;
    int total = (padRows * cols) >> 2;
    if (i >= total) return;
    int r = (i * 4) / cols;
    ushort4 o;
    if (r < rows) {
        float4 v = *(const float4*)(in + (size_t)i * 4);
        o = make_ushort4(f2h(v.x), f2h(v.y), f2h(v.z), f2h(v.w));
    } else {
        o = make_ushort4(0, 0, 0, 0);
    }
    *(ushort4*)(out + (size_t)i * 4) = o;
}

// All four weight transposes in one launch (f32 -> f16, [K,Nc] -> [Nc,K]).
__global__ void transpose_all_kernel(
    const float* __restrict__ W1, const float* __restrict__ W2,
    const float* __restrict__ Wm, const float* __restrict__ Wl,
    unsigned short* __restrict__ W1t, unsigned short* __restrict__ W2t,
    unsigned short* __restrict__ WmlT) {
    int i = blockIdx.x * blockDim.x + threadIdx.x;
    if (i < 65536) {
        int k = i >> 8, n = i & 255;
        W1t[(size_t)n * 256 + k] = f2h(W1[i]);
    } else if (i < 65536 + 131072) {
        int j = i - 65536;
        int k = j >> 9, n = j & 511;
        W2t[(size_t)n * 256 + k] = f2h(W2[j]);
    } else if (i < 65536 + 131072 + 65536) {
        int j = i - 196608;
        int k = j >> 7, n = j & 127;
        WmlT[(size_t)n * 512 + k] = f2h(Wm[j]);
    } else if (i < 65536 + 131072 + 131072) {
        int j = i - 262144;
        int k = j >> 7, n = j & 127;
        WmlT[(size_t)(128 + n) * 512 + k] = f2h(Wl[j]);
    }
}

// ---------------- f16 MFMA GEMM + no-atomic attention-logit epilogue ----------------
// C[M,Nc] = A[Mp,K] @ Bt[Nc,K]^T; 128x128 tile, BK=32, 256 threads (2x2 waves),
// register staging -> LDS. Epilogue computes al_s/al_d via per-wave 16-lane
// reductions -> LDS -> direct stores (each (row, head) owned by one block).

__global__ __launch_bounds__(256) void gemm_f16_kernel(
    const unsigned short* __restrict__ A, const unsigned short* __restrict__ Bt,
    unsigned short* __restrict__ C, int M, int K, int Nc,
    float* __restrict__ al_s, float* __restrict__ al_d,
    const float* __restrict__ aslo, const float* __restrict__ adlo,
    const float* __restrict__ ashi, const float* __restrict__ adhi,
    int csplit, int Chead, int H) {
    __shared__ short As[128 * 32];
    __shared__ short Bs[128 * 32];
    __shared__ float salS[128][4];
    __shared__ float salD[128][4];
    int tid = threadIdx.x;
    int bm = blockIdx.y * 128;
    int bn = blockIdx.x * 128;
    int wave = tid >> 6, lane = tid & 63;
    int wm = (wave >> 1) * 64, wn = (wave & 1) * 64;
    int lm = lane & 15, lq = lane >> 4;

    f32x4 acc[4][4] = {};

    int c0 = tid, c1 = tid + 256;
    const unsigned short* Ap0 = A + (size_t)(bm + (c0 >> 2)) * K + (c0 & 3) * 8;
    const unsigned short* Ap1 = A + (size_t)(bm + (c1 >> 2)) * K + (c1 & 3) * 8;
    const unsigned short* Bp0 = Bt + (size_t)(bn + (c0 >> 2)) * K + (c0 & 3) * 8;
    const unsigned short* Bp1 = Bt + (size_t)(bn + (c1 >> 2)) * K + (c1 & 3) * 8;

    for (int kk = 0; kk < K; kk += 32) {
        short8 a0 = *(const short8*)(Ap0 + kk);
        short8 a1 = *(const short8*)(Ap1 + kk);
        short8 b0 = *(const short8*)(Bp0 + kk);
        short8 b1 = *(const short8*)(Bp1 + kk);
        __syncthreads();
        *(short8*)&As[c0 * 8] = a0;
        *(short8*)&As[c1 * 8] = a1;
        *(short8*)&Bs[c0 * 8] = b0;
        *(short8*)&Bs[c1 * 8] = b1;
        __syncthreads();
        half8 af[4], bf[4];
#pragma unroll
        for (int t = 0; t < 4; t++) {
            af[t] = *(const half8*)&As[(wm + t * 16 + lm) * 32 + lq * 8];
            bf[t] = *(const half8*)&Bs[(wn + t * 16 + lm) * 32 + lq * 8];
        }
#pragma unroll
        for (int tm = 0; tm < 4; tm++)
#pragma unroll
            for (int tn = 0; tn < 4; tn++)
                acc[tm][tn] = __builtin_amdgcn_mfma_f32_16x16x32_f16(
                    af[tm], bf[tn], acc[tm][tn], 0, 0, 0);
    }

    // C store (f16)
#pragma unroll
    for (int tm = 0; tm < 4; tm++) {
#pragma unroll
        for (int r = 0; r < 4; r++) {
            int row = bm + wm + tm * 16 + lq * 4 + r;
            if (row < M) {
#pragma unroll
                for (int tn = 0; tn < 4; tn++) {
                    int col = bn + wn + tn * 16 + lm;
                    C[(size_t)row * Nc + col] = f2h(acc[tm][tn][r]);
                }
            }
        }
    }

    // attention-logit partial dots -> LDS (each (row, 32-col group) owned by
    // exactly one wave; no races)
    float asv[4], adv[4];
#pragma unroll
    for (int tn = 0; tn < 4; tn++) {
        int col = bn + wn + tn * 16 + lm;
        bool hi = col >= csplit;
        int cc = hi ? col - csplit : col;
        asv[tn] = hi ? ashi[cc] : aslo[cc];
        adv[tn] = hi ? adhi[cc] : adlo[cc];
    }
    int gb = wn >> 5;  // 0 or 2
#pragma unroll
    for (int tm = 0; tm < 4; tm++) {
#pragma unroll
        for (int r = 0; r < 4; r++) {
#pragma unroll
            for (int p = 0; p < 2; p++) {
                float s1 = acc[tm][2 * p][r] * asv[2 * p]
                         + acc[tm][2 * p + 1][r] * asv[2 * p + 1];
                float s2 = acc[tm][2 * p][r] * adv[2 * p]
                         + acc[tm][2 * p + 1][r] * adv[2 * p + 1];
#pragma unroll
                for (int off = 8; off >= 1; off >>= 1) {
                    s1 += __shfl_xor(s1, off);
                    s2 += __shfl_xor(s2, off);
                }
                if (lm == 0) {
                    int rl = wm + tm * 16 + lq * 4 + r;
                    salS[rl][gb + p] = s1;
                    salD[rl][gb + p] = s2;
                }
            }
        }
    }
    __syncthreads();
    if (tid < 128) {
        int row = bm + tid;
        if (row < M) {
            int hb = bn / Chead;       // first head in this col-block
            int HB = 128 / Chead;      // heads per col-block (1, 2, or 4)
            int GH = Chead >> 5;       // 32-col groups per head
            for (int i = 0; i < HB; i++) {
                float ss = 0.f, sd = 0.f;
                for (int j = 0; j < GH; j++) {
                    ss += salS[tid][i * GH + j];
                    sd += salD[tid][i * GH + j];
                }
                al_s[(size_t)row * H + hb + i] = ss;
                al_d[(size_t)row * H + hb + i] = sd;
            }
        }
    }
}

// ---------------- fused per-node softmax + aggregate, 4 nodes/block ----------------
// 4 waves/block, each wave owns one dst node. Lane-per-edge softmax via
// butterfly shuffles; alpha parked in LDS; gather-aggregate with PACKED F16
// FMAs (V channels/lane, zero converts in the inner loop), 8-edge unroll.
// MODE 0: concat + bias + ReLU, f16 out. MODE 1: 8 heads x 32ch -> head-mean
// over groups 0-3 / 4-7 + bias, f32 out1/out2.

template <int H4, int V, int MODE>
__global__ __launch_bounds__(256) void gat_fused_kernel(
    const int* __restrict__ rp, const int* __restrict__ csrc,
    const float* __restrict__ al_s, const float* __restrict__ al_d,
    const unsigned short* __restrict__ h,
    const float* __restrict__ bias1, const float* __restrict__ bias2,
    void* __restrict__ out1v, void* __restrict__ out2v, int HC, int C, int N) {
    const int H = 4 * H4;
    __shared__ int lds_src[4][64];
    __shared__ float lds_alpha[4][64 * 4 * H4];
    __shared__ float shred[4][256];
    int wv = threadIdx.x >> 6;
    int lane = threadIdx.x & 63;
    int n = blockIdx.x * 4 + wv;
    if (n >= N) return;
    int beg = rp[n], end = rp[n + 1];
    int deg = end - beg;

    float ad[H];
#pragma unroll
    for (int g = 0; g < H4; g++)
        *(float4*)&ad[g * 4] = *(const float4*)(al_d + (size_t)n * H + g * 4);

    int ch = lane * V;
    int hh = ch / C;
    half8 acc8 = {};
    half4 acc4 = {};

    if (deg <= 64) {
        bool act = lane < deg;
        int s = act ? csrc[beg + lane] : 0;
        float v[H], m[H], ex[H], sum[H];
#pragma unroll
        for (int g = 0; g < H4; g++) {
            float4 as = *(const float4*)(al_s + (size_t)s * H + g * 4);
            v[g * 4 + 0] = lrelu(as.x + ad[g * 4 + 0]);
            v[g * 4 + 1] = lrelu(as.y + ad[g * 4 + 1]);
            v[g * 4 + 2] = lrelu(as.z + ad[g * 4 + 2]);
            v[g * 4 + 3] = lrelu(as.w + ad[g * 4 + 3]);
        }
#pragma unroll
        for (int j = 0; j < H; j++) m[j] = act ? v[j] : -3.402823466e38f;
#pragma unroll
        for (int off = 32; off >= 1; off >>= 1)
#pragma unroll
            for (int j = 0; j < H; j++) m[j] = fmaxf(m[j], __shfl_xor(m[j], off));
#pragma unroll
        for (int j = 0; j < H; j++) {
            ex[j] = act ? __expf(v[j] - m[j]) : 0.f;
            sum[j] = ex[j];
        }
#pragma unroll
        for (int off = 32; off >= 1; off >>= 1)
#pragma unroll
            for (int j = 0; j < H; j++) sum[j] += __shfl_xor(sum[j], off);
        if (act) {
            lds_src[wv][lane] = s;
#pragma unroll
            for (int g = 0; g < H4; g++) {
                float4 o;
                o.x = ex[g * 4 + 0] / (sum[g * 4 + 0] + 1e-16f);
                o.y = ex[g * 4 + 1] / (sum[g * 4 + 1] + 1e-16f);
                o.z = ex[g * 4 + 2] / (sum[g * 4 + 2] + 1e-16f);
                o.w = ex[g * 4 + 3] / (sum[g * 4 + 3] + 1e-16f);
                *(float4*)&lds_alpha[wv][lane * H + g * 4] = o;
            }
        }
        // wave-local LDS write->read (lockstep wave, compiler lgkmcnt ordering)
        int t = 0;
        for (; t + 8 <= deg; t += 8) {
            int ss[8]; float av[8];
#pragma unroll
            for (int u = 0; u < 8; u++) {
                ss[u] = lds_src[wv][t + u];
                av[u] = lds_alpha[wv][(t + u) * H + hh];
            }
            if constexpr (V == 8) {
                half8 hv[8];
#pragma unroll
                for (int u = 0; u < 8; u++)
                    hv[u] = *(const half8*)(h + (size_t)ss[u] * HC + ch);
#pragma unroll
                for (int u = 0; u < 8; u++) {
                    _Float16 ah = (_Float16)av[u];
                    half8 a2;
#pragma unroll
                    for (int i = 0; i < 8; i++) a2[i] = ah;
                    acc8 += hv[u] * a2;
                }
            } else {
                half4 hv[8];
#pragma unroll
                for (int u = 0; u < 8; u++)
                    hv[u] = *(const half4*)(h + (size_t)ss[u] * HC + ch);
#pragma unroll
                for (int u = 0; u < 8; u++) {
                    _Float16 ah = (_Float16)av[u];
                    half4 a2;
#pragma unroll
                    for (int i = 0; i < 4; i++) a2[i] = ah;
                    acc4 += hv[u] * a2;
                }
            }
        }
        for (; t < deg; t++) {
            int s2 = lds_src[wv][t];
            _Float16 ah = (_Float16)lds_alpha[wv][t * H + hh];
            if constexpr (V == 8) {
                half8 hv = *(const half8*)(h + (size_t)s2 * HC + ch);
                half8 a2;
#pragma unroll
                for (int i = 0; i < 8; i++) a2[i] = ah;
                acc8 += hv * a2;
            } else {
                half4 hv = *(const half4*)(h + (size_t)s2 * HC + ch);
                half4 a2;
#pragma unroll
                for (int i = 0; i < 4; i++) a2[i] = ah;
                acc4 += hv * a2;
            }
        }
    } else {
        // general path (deg > 64): strided stats with recompute, chunked agg
        float m[H], sum[H];
#pragma unroll
        for (int j = 0; j < H; j++) m[j] = -3.402823466e38f;
        for (int e = beg + lane; e < end; e += 64) {
            int s = csrc[e];
#pragma unroll
            for (int g = 0; g < H4; g++) {
                float4 as = *(const float4*)(al_s + (size_t)s * H + g * 4);
                m[g * 4 + 0] = fmaxf(m[g * 4 + 0], lrelu(as.x + ad[g * 4 + 0]));
                m[g * 4 + 1] = fmaxf(m[g * 4 + 1], lrelu(as.y + ad[g * 4 + 1]));
                m[g * 4 + 2] = fmaxf(m[g * 4 + 2], lrelu(as.z + ad[g * 4 + 2]));
                m[g * 4 + 3] = fmaxf(m[g * 4 + 3], lrelu(as.w + ad[g * 4 + 3]));
            }
        }
#pragma unroll
        for (int off = 32; off >= 1; off >>= 1)
#pragma unroll
            for (int j = 0; j < H; j++) m[j] = fmaxf(m[j], __shfl_xor(m[j], off));
#pragma unroll
        for (int j = 0; j < H; j++) sum[j] = 0.f;
        for (int e = beg + lane; e < end; e += 64) {
            int s = csrc[e];
#pragma unroll
            for (int g = 0; g < H4; g++) {
                float4 as = *(const float4*)(al_s + (size_t)s * H + g * 4);
                sum[g * 4 + 0] += __expf(lrelu(as.x + ad[g * 4 + 0]) - m[g * 4 + 0]);
                sum[g * 4 + 1] += __expf(lrelu(as.y + ad[g * 4 + 1]) - m[g * 4 + 1]);
                sum[g * 4 + 2] += __expf(lrelu(as.z + ad[g * 4 + 2]) - m[g * 4 + 2]);
                sum[g * 4 + 3] += __expf(lrelu(as.w + ad[g * 4 + 3]) - m[g * 4 + 3]);
            }
        }
#pragma unroll
        for (int off = 32; off >= 1; off >>= 1)
#pragma unroll
            for (int j = 0; j < H; j++) sum[j] += __shfl_xor(sum[j], off);
        float r[H];
#pragma unroll
        for (int j = 0; j < H; j++) r[j] = 1.0f / (sum[j] + 1e-16f);
        for (int base = beg; base < end; base += 64) {
            int cn = end - base < 64 ? end - base : 64;
            if (lane < cn) {
                int s = csrc[base + lane];
                lds_src[wv][lane] = s;
#pragma unroll
                for (int g = 0; g < H4; g++) {
                    float4 as = *(const float4*)(al_s + (size_t)s * H + g * 4);
                    float4 o;
                    o.x = __expf(lrelu(as.x + ad[g * 4 + 0]) - m[g * 4 + 0]) * r[g * 4 + 0];
                    o.y = __expf(lrelu(as.y + ad[g * 4 + 1]) - m[g * 4 + 1]) * r[g * 4 + 1];
                    o.z = __expf(lrelu(as.z + ad[g * 4 + 2]) - m[g * 4 + 2]) * r[g * 4 + 2];
                    o.w = __expf(lrelu(as.w + ad[g * 4 + 3]) - m[g * 4 + 3]) * r[g * 4 + 3];
                    *(float4*)&lds_alpha[wv][lane * H + g * 4] = o;
                }
            }
            for (int t = 0; t < cn; t++) {
                int s2 = lds_src[wv][t];
                _Float16 ah = (_Float16)lds_alpha[wv][t * H + hh];
                if constexpr (V == 8) {
                    half8 hv = *(const half8*)(h + (size_t)s2 * HC + ch);
                    half8 a2;
#pragma unroll
                    for (int i = 0; i < 8; i++) a2[i] = ah;
                    acc8 += hv * a2;
                } else {
                    half4 hv = *(const half4*)(h + (size_t)s2 * HC + ch);
                    half4 a2;
#pragma unroll
                    for (int i = 0; i < 4; i++) a2[i] = ah;
                    acc4 += hv * a2;
                }
            }
        }
    }

    float accf[V];
#pragma unroll
    for (int j = 0; j < V; j++)
        accf[j] = (V == 8) ? (float)acc8[j] : (float)acc4[j];

    if constexpr (MODE == 0) {
        unsigned short* out = (unsigned short*)out1v;
        unsigned short o[V];
#pragma unroll
        for (int j = 0; j < V; j++)
            o[j] = f2h(fmaxf(accf[j] + bias1[ch + j], 0.f));
        if constexpr (V == 8) {
            short8 ov;
#pragma unroll
            for (int j = 0; j < 8; j++) ov[j] = (short)o[j];
            *(short8*)(out + (size_t)n * HC + ch) = ov;
        } else {
            *(ushort4*)(out + (size_t)n * HC + ch) = make_ushort4(o[0], o[1], o[2], o[3]);
        }
    } else {
        // MODE 1: HC=256, V=4, 8 heads x 32ch -> mean over heads 0-3 / 4-7
        *(float4*)&shred[wv][ch] = make_float4(accf[0], accf[1], accf[2], accf[3]);
        if (lane < 32) {
            float v1 = (shred[wv][lane] + shred[wv][lane + 32] + shred[wv][lane + 64]
                        + shred[wv][lane + 96]) * 0.25f + bias1[lane];
            float v2 = (shred[wv][lane + 128] + shred[wv][lane + 160]
                        + shred[wv][lane + 192] + shred[wv][lane + 224]) * 0.25f
                       + bias2[lane];
            ((float*)out1v)[(size_t)n * 32 + lane] = v1;
            ((float*)out2v)[(size_t)n * 32 + lane] = v2;
        }
    }
}

// ---------------- orchestration ----------------

extern "C" void kernel_launch(void* const* d_in, const int* in_sizes, int n_in,
                              void* d_out, int out_size, void* d_ws, size_t ws_size,
                              hipStream_t stream) {
    (void)n_in; (void)out_size; (void)ws_size;
    const float* x   = (const float*)d_in[0];
    const int*   ei  = (const int*)d_in[1];
    const float* W1  = (const float*)d_in[2];
    const float* as1 = (const float*)d_in[3];
    const float* ad1 = (const float*)d_in[4];
    const float* b1  = (const float*)d_in[5];
    const float* W2  = (const float*)d_in[6];
    const float* as2 = (const float*)d_in[7];
    const float* ad2 = (const float*)d_in[8];
    const float* b2  = (const float*)d_in[9];
    const float* Wm  = (const float*)d_in[10];
    const float* a_sm = (const float*)d_in[11];
    const float* a_dm = (const float*)d_in[12];
    const float* bm  = (const float*)d_in[13];
    const float* Wl  = (const float*)d_in[14];
    const float* a_sl = (const float*)d_in[15];
    const float* a_dl = (const float*)d_in[16];
    const float* bl  = (const float*)d_in[17];
    float* outp = (float*)d_out;

    const int N  = in_sizes[0] / 256;   // 30000
    const int E  = in_sizes[1] / 2;     // 480000
    const int ET = E + N;               // with self loops
    const int gM = (N + 127) / 128;     // 235
    const int Mp = gM * 128;            // 30080

    auto align_up = [](size_t v) { return (v + 255) & ~(size_t)255; };
    char* w = (char*)d_ws;
    int* row_ptr = (int*)w;  w += align_up((size_t)(N + 1) * 4);
    int* cnt     = (int*)w;  w += align_up((size_t)N * 4);
    int* csrc    = (int*)w;  w += align_up((size_t)ET * 4);
    float* al_s  = (float*)w; w += align_up((size_t)N * 8 * 4);
    float* al_d  = (float*)w; w += align_up((size_t)N * 8 * 4);
    unsigned short* xb   = (unsigned short*)w; w += align_up((size_t)Mp * 256 * 2);
    unsigned short* W1t  = (unsigned short*)w; w += align_up((size_t)256 * 256 * 2);
    unsigned short* W2t  = (unsigned short*)w; w += align_up((size_t)512 * 256 * 2);
    unsigned short* WmlT = (unsigned short*)w; w += align_up((size_t)256 * 512 * 2);
    unsigned short* bufH = (unsigned short*)w; w += align_up((size_t)Mp * 512 * 2);
    unsigned short* bufO = (unsigned short*)w; w += align_up((size_t)Mp * 512 * 2);

    // ---- CSR build ----
    int gzE = (ET + 255) / 256;
    hipMemsetAsync(cnt, 0, (size_t)N * 4, stream);
    count_edges_kernel<<<gzE, 256, 0, stream>>>(ei, E, N, cnt);
    scan_kernel<<<1, 1024, 0, stream>>>(cnt, row_ptr, N);   // re-zeroes cnt
    scatter_edges_kernel<<<gzE, 256, 0, stream>>>(ei, E, N, row_ptr, cnt, csrc);

    // ---- dtype prep ----
    f32_to_f16_pad4_kernel<<<((Mp * 256 / 4) + 255) / 256, 256, 0, stream>>>(
        x, xb, N, 256, Mp);
    transpose_all_kernel<<<(393216 + 255) / 256, 256, 0, stream>>>(
        W1, W2, Wm, Wl, W1t, W2t, WmlT);

    int gF = (N + 3) / 4;

    // ---- Layer 1: GAT(256 -> 4x64, concat) + ReLU ----
    gemm_f16_kernel<<<dim3(2, gM), 256, 0, stream>>>(
        xb, W1t, bufH, N, 256, 256, al_s, al_d, as1, ad1, as1, ad1, 256, 64, 4);
    gat_fused_kernel<1, 4, 0><<<gF, 256, 0, stream>>>(
        row_ptr, csrc, al_s, al_d, bufH, b1, nullptr, bufO, nullptr, 256, 64, N);

    // ---- Layer 2: GAT(256 -> 4x128, concat) + ReLU ----
    gemm_f16_kernel<<<dim3(4, gM), 256, 0, stream>>>(
        bufO, W2t, bufH, N, 256, 512, al_s, al_d, as2, ad2, as2, ad2, 512, 128, 4);
    gat_fused_kernel<1, 8, 0><<<gF, 256, 0, stream>>>(
        row_ptr, csrc, al_s, al_d, bufH, b2, nullptr, bufO, nullptr, 512, 128, N);

    // ---- Layers 3+4 batched: GAT(512 -> 8x32, mean per 4-head group) ----
    gemm_f16_kernel<<<dim3(2, gM), 256, 0, stream>>>(
        bufO, WmlT, bufH, N, 512, 256, al_s, al_d, a_sm, a_dm, a_sl, a_dl, 128, 32, 8);
    gat_fused_kernel<2, 4, 1><<<gF, 256, 0, stream>>>(
        row_ptr, csrc, al_s, al_d, bufH, bm, bl, outp, outp + (size_t)N * 32, 256, 32, N);
}

// Round 11
// 446.684 us; speedup vs baseline: 1.2096x; 1.0096x over previous
//
#include <hip/hip_runtime.h>
#include <cstddef>

typedef __attribute__((ext_vector_type(8))) short short8;
typedef __attribute__((ext_vector_type(4))) float f32x4;
typedef __attribute__((ext_vector_type(8))) _Float16 half8;
typedef __attribute__((ext_vector_type(4))) _Float16 half4;

__device__ __forceinline__ unsigned short f2h(float f) {
    union { _Float16 h; unsigned short u; } x; x.h = (_Float16)f; return x.u;
}
__device__ __forceinline__ float lrelu(float v) { return v > 0.f ? v : 0.2f * v; }

// ---------------- CSR build ----------------

__global__ void count_edges_kernel(const int* __restrict__ ei, int E, int N,
                                   int* __restrict__ cnt) {
    int e = blockIdx.x * blockDim.x + threadIdx.x;
    if (e >= E + N) return;
    int d = (e < E) ? ei[E + e] : (e - E);  // self loops appended
    atomicAdd(&cnt[d], 1);
}

// single block, 1024 threads; also re-zeroes cnt for the scatter cursor.
__global__ void scan_kernel(int* __restrict__ cnt, int* __restrict__ rp, int n) {
    __shared__ int sh[1024];
    int t = threadIdx.x;
    int chunk = (n + 1023) >> 10;
    int beg = t * chunk;
    int end = beg + chunk < n ? beg + chunk : n;
    int local = 0;
    for (int i = beg; i < end; i++) local += cnt[i];
    sh[t] = local;
    __syncthreads();
    for (int off = 1; off < 1024; off <<= 1) {
        int v = (t >= off) ? sh[t - off] : 0;
        __syncthreads();
        sh[t] += v;
        __syncthreads();
    }
    int run = (t == 0) ? 0 : sh[t - 1];
    for (int i = beg; i < end; i++) {
        int c = cnt[i];
        cnt[i] = 0;
        run += c;
        rp[i + 1] = run;
    }
    if (t == 0) rp[0] = 0;
}

__global__ void scatter_edges_kernel(const int* __restrict__ ei, int E, int N,
                                     const int* __restrict__ rp, int* __restrict__ cur,
                                     int* __restrict__ csrc) {
    int e = blockIdx.x * blockDim.x + threadIdx.x;
    if (e >= E + N) return;
    int s, d;
    if (e < E) { s = ei[e]; d = ei[E + e]; } else { s = e - E; d = s; }
    int pos = rp[d] + atomicAdd(&cur[d], 1);
    csrc[pos] = s;
}

// ---------------- dtype prep ----------------

__global__ void f32_to_f16_pad4_kernel(const float* __restrict__ in,
                                       unsigned short* __restrict__ out,
                                       int rows, int cols, int padRows) {
    int i = blockIdx.x * blockDim.x + threadIdx.x;
    int total = (padRows * cols) >> 2;
    if (i >= total) return;
    int r = (i * 4) / cols;
    ushort4 o;
    if (r < rows) {
        float4 v = *(const float4*)(in + (size_t)i * 4);
        o = make_ushort4(f2h(v.x), f2h(v.y), f2h(v.z), f2h(v.w));
    } else {
        o = make_ushort4(0, 0, 0, 0);
    }
    *(ushort4*)(out + (size_t)i * 4) = o;
}

// All four weight transposes in one launch (f32 -> f16, [K,Nc] -> [Nc,K]).
__global__ void transpose_all_kernel(
    const float* __restrict__ W1, const float* __restrict__ W2,
    const float* __restrict__ Wm, const float* __restrict__ Wl,
    unsigned short* __restrict__ W1t, unsigned short* __restrict__ W2t,
    unsigned short* __restrict__ WmlT) {
    int i = blockIdx.x * blockDim.x + threadIdx.x;
    if (i < 65536) {
        int k = i >> 8, n = i & 255;
        W1t[(size_t)n * 256 + k] = f2h(W1[i]);
    } else if (i < 65536 + 131072) {
        int j = i - 65536;
        int k = j >> 9, n = j & 511;
        W2t[(size_t)n * 256 + k] = f2h(W2[j]);
    } else if (i < 65536 + 131072 + 65536) {
        int j = i - 196608;
        int k = j >> 7, n = j & 127;
        WmlT[(size_t)n * 512 + k] = f2h(Wm[j]);
    } else if (i < 65536 + 131072 + 131072) {
        int j = i - 262144;
        int k = j >> 7, n = j & 127;
        WmlT[(size_t)(128 + n) * 512 + k] = f2h(Wl[j]);
    }
}

// ---------------- f16 MFMA GEMM + no-atomic attention-logit epilogue ----------------
// C[M,Nc] = A[Mp,K] @ Bt[Nc,K]^T; 64x128 tile (BM=64 for 2x the wave-parallelism
// at these small-N shapes), BK=32, 256 threads (2x2 waves of 32x64).
// Epilogue: cols [bn,bn+128) contain COMPLETE heads; per-wave 16-lane reduce ->
// LDS -> 64 row-threads sum groups -> direct stores of al_s/al_d (no atomics).

__global__ __launch_bounds__(256) void gemm_f16_kernel(
    const unsigned short* __restrict__ A, const unsigned short* __restrict__ Bt,
    unsigned short* __restrict__ C, int M, int K, int Nc,
    float* __restrict__ al_s, float* __restrict__ al_d,
    const float* __restrict__ aslo, const float* __restrict__ adlo,
    const float* __restrict__ ashi, const float* __restrict__ adhi,
    int csplit, int Chead, int H) {
    __shared__ short As[64 * 32];
    __shared__ short Bs[128 * 32];
    __shared__ float salS[64][4];
    __shared__ float salD[64][4];
    int tid = threadIdx.x;
    int bm = blockIdx.y * 64;
    int bn = blockIdx.x * 128;
    int wave = tid >> 6, lane = tid & 63;
    int wm = (wave >> 1) * 32, wn = (wave & 1) * 64;
    int lm = lane & 15, lq = lane >> 4;

    f32x4 acc[2][4] = {};

    // A staging: 64x32 = 256 chunks of short8, 1/thread
    // B staging: 128x32 = 512 chunks, 2/thread
    int c0 = tid, c1 = tid + 256;
    const unsigned short* Ap0 = A + (size_t)(bm + (c0 >> 2)) * K + (c0 & 3) * 8;
    const unsigned short* Bp0 = Bt + (size_t)(bn + (c0 >> 2)) * K + (c0 & 3) * 8;
    const unsigned short* Bp1 = Bt + (size_t)(bn + (c1 >> 2)) * K + (c1 & 3) * 8;

    for (int kk = 0; kk < K; kk += 32) {
        short8 a0 = *(const short8*)(Ap0 + kk);
        short8 b0 = *(const short8*)(Bp0 + kk);
        short8 b1 = *(const short8*)(Bp1 + kk);
        __syncthreads();
        *(short8*)&As[c0 * 8] = a0;
        *(short8*)&Bs[c0 * 8] = b0;
        *(short8*)&Bs[c1 * 8] = b1;
        __syncthreads();
        half8 af[2], bf[4];
#pragma unroll
        for (int t = 0; t < 2; t++)
            af[t] = *(const half8*)&As[(wm + t * 16 + lm) * 32 + lq * 8];
#pragma unroll
        for (int t = 0; t < 4; t++)
            bf[t] = *(const half8*)&Bs[(wn + t * 16 + lm) * 32 + lq * 8];
#pragma unroll
        for (int tm = 0; tm < 2; tm++)
#pragma unroll
            for (int tn = 0; tn < 4; tn++)
                acc[tm][tn] = __builtin_amdgcn_mfma_f32_16x16x32_f16(
                    af[tm], bf[tn], acc[tm][tn], 0, 0, 0);
    }

    // C store (f16)
#pragma unroll
    for (int tm = 0; tm < 2; tm++) {
#pragma unroll
        for (int r = 0; r < 4; r++) {
            int row = bm + wm + tm * 16 + lq * 4 + r;
            if (row < M) {
#pragma unroll
                for (int tn = 0; tn < 4; tn++) {
                    int col = bn + wn + tn * 16 + lm;
                    C[(size_t)row * Nc + col] = f2h(acc[tm][tn][r]);
                }
            }
        }
    }

    // attention-logit partial dots -> LDS (each (row, 32-col group) owned by
    // exactly one wave; no races)
    float asv[4], adv[4];
#pragma unroll
    for (int tn = 0; tn < 4; tn++) {
        int col = bn + wn + tn * 16 + lm;
        bool hi = col >= csplit;
        int cc = hi ? col - csplit : col;
        asv[tn] = hi ? ashi[cc] : aslo[cc];
        adv[tn] = hi ? adhi[cc] : adlo[cc];
    }
    int gb = wn >> 5;  // 0 or 2
#pragma unroll
    for (int tm = 0; tm < 2; tm++) {
#pragma unroll
        for (int r = 0; r < 4; r++) {
#pragma unroll
            for (int p = 0; p < 2; p++) {
                float s1 = acc[tm][2 * p][r] * asv[2 * p]
                         + acc[tm][2 * p + 1][r] * asv[2 * p + 1];
                float s2 = acc[tm][2 * p][r] * adv[2 * p]
                         + acc[tm][2 * p + 1][r] * adv[2 * p + 1];
#pragma unroll
                for (int off = 8; off >= 1; off >>= 1) {
                    s1 += __shfl_xor(s1, off);
                    s2 += __shfl_xor(s2, off);
                }
                if (lm == 0) {
                    int rl = wm + tm * 16 + lq * 4 + r;
                    salS[rl][gb + p] = s1;
                    salD[rl][gb + p] = s2;
                }
            }
        }
    }
    __syncthreads();
    if (tid < 64) {
        int row = bm + tid;
        if (row < M) {
            int hb = bn / Chead;       // first head in this col-block
            int HB = 128 / Chead;      // heads per col-block (1, 2, or 4)
            int GH = Chead >> 5;       // 32-col groups per head
            for (int i = 0; i < HB; i++) {
                float ss = 0.f, sd = 0.f;
                for (int j = 0; j < GH; j++) {
                    ss += salS[tid][i * GH + j];
                    sd += salD[tid][i * GH + j];
                }
                al_s[(size_t)row * H + hb + i] = ss;
                al_d[(size_t)row * H + hb + i] = sd;
            }
        }
    }
}

// ---------------- fused per-node softmax + aggregate, 4 nodes/block ----------------
// 4 waves/block, each wave owns one dst node. Lane-per-edge softmax via
// butterfly shuffles; alpha parked in LDS; gather-aggregate with PACKED F16
// FMAs (V channels/lane), 8-edge unroll.
// MODE 0: concat + bias + ReLU, f16 out. MODE 1: 8 heads x 32ch -> head-mean
// over groups 0-3 / 4-7 + bias, f32 out1/out2.

template <int H4, int V, int MODE>
__global__ __launch_bounds__(256) void gat_fused_kernel(
    const int* __restrict__ rp, const int* __restrict__ csrc,
    const float* __restrict__ al_s, const float* __restrict__ al_d,
    const unsigned short* __restrict__ h,
    const float* __restrict__ bias1, const float* __restrict__ bias2,
    void* __restrict__ out1v, void* __restrict__ out2v, int HC, int C, int N) {
    const int H = 4 * H4;
    __shared__ int lds_src[4][64];
    __shared__ float lds_alpha[4][64 * 4 * H4];
    __shared__ float shred[4][256];
    int wv = threadIdx.x >> 6;
    int lane = threadIdx.x & 63;
    int n = blockIdx.x * 4 + wv;
    if (n >= N) return;
    int beg = rp[n], end = rp[n + 1];
    int deg = end - beg;

    float ad[H];
#pragma unroll
    for (int g = 0; g < H4; g++)
        *(float4*)&ad[g * 4] = *(const float4*)(al_d + (size_t)n * H + g * 4);

    int ch = lane * V;
    int hh = ch / C;
    half8 acc8 = {};
    half4 acc4 = {};

    if (deg <= 64) {
        bool act = lane < deg;
        int s = act ? csrc[beg + lane] : 0;
        float v[H], m[H], ex[H], sum[H];
#pragma unroll
        for (int g = 0; g < H4; g++) {
            float4 as = *(const float4*)(al_s + (size_t)s * H + g * 4);
            v[g * 4 + 0] = lrelu(as.x + ad[g * 4 + 0]);
            v[g * 4 + 1] = lrelu(as.y + ad[g * 4 + 1]);
            v[g * 4 + 2] = lrelu(as.z + ad[g * 4 + 2]);
            v[g * 4 + 3] = lrelu(as.w + ad[g * 4 + 3]);
        }
#pragma unroll
        for (int j = 0; j < H; j++) m[j] = act ? v[j] : -3.402823466e38f;
#pragma unroll
        for (int off = 32; off >= 1; off >>= 1)
#pragma unroll
            for (int j = 0; j < H; j++) m[j] = fmaxf(m[j], __shfl_xor(m[j], off));
#pragma unroll
        for (int j = 0; j < H; j++) {
            ex[j] = act ? __expf(v[j] - m[j]) : 0.f;
            sum[j] = ex[j];
        }
#pragma unroll
        for (int off = 32; off >= 1; off >>= 1)
#pragma unroll
            for (int j = 0; j < H; j++) sum[j] += __shfl_xor(sum[j], off);
        if (act) {
            lds_src[wv][lane] = s;
#pragma unroll
            for (int g = 0; g < H4; g++) {
                float4 o;
                o.x = ex[g * 4 + 0] / (sum[g * 4 + 0] + 1e-16f);
                o.y = ex[g * 4 + 1] / (sum[g * 4 + 1] + 1e-16f);
                o.z = ex[g * 4 + 2] / (sum[g * 4 + 2] + 1e-16f);
                o.w = ex[g * 4 + 3] / (sum[g * 4 + 3] + 1e-16f);
                *(float4*)&lds_alpha[wv][lane * H + g * 4] = o;
            }
        }
        // wave-local LDS write->read (lockstep wave, compiler lgkmcnt ordering)
        int t = 0;
        for (; t + 8 <= deg; t += 8) {
            int ss[8]; float av[8];
#pragma unroll
            for (int u = 0; u < 8; u++) {
                ss[u] = lds_src[wv][t + u];
                av[u] = lds_alpha[wv][(t + u) * H + hh];
            }
            if constexpr (V == 8) {
                half8 hv[8];
#pragma unroll
                for (int u = 0; u < 8; u++)
                    hv[u] = *(const half8*)(h + (size_t)ss[u] * HC + ch);
#pragma unroll
                for (int u = 0; u < 8; u++) {
                    _Float16 ah = (_Float16)av[u];
                    half8 a2;
#pragma unroll
                    for (int i = 0; i < 8; i++) a2[i] = ah;
                    acc8 += hv[u] * a2;
                }
            } else {
                half4 hv[8];
#pragma unroll
                for (int u = 0; u < 8; u++)
                    hv[u] = *(const half4*)(h + (size_t)ss[u] * HC + ch);
#pragma unroll
                for (int u = 0; u < 8; u++) {
                    _Float16 ah = (_Float16)av[u];
                    half4 a2;
#pragma unroll
                    for (int i = 0; i < 4; i++) a2[i] = ah;
                    acc4 += hv[u] * a2;
                }
            }
        }
        for (; t < deg; t++) {
            int s2 = lds_src[wv][t];
            _Float16 ah = (_Float16)lds_alpha[wv][t * H + hh];
            if constexpr (V == 8) {
                half8 hv = *(const half8*)(h + (size_t)s2 * HC + ch);
                half8 a2;
#pragma unroll
                for (int i = 0; i < 8; i++) a2[i] = ah;
                acc8 += hv * a2;
            } else {
                half4 hv = *(const half4*)(h + (size_t)s2 * HC + ch);
                half4 a2;
#pragma unroll
                for (int i = 0; i < 4; i++) a2[i] = ah;
                acc4 += hv * a2;
            }
        }
    } else {
        // general path (deg > 64): strided stats with recompute, chunked agg
        float m[H], sum[H];
#pragma unroll
        for (int j = 0; j < H; j++) m[j] = -3.402823466e38f;
        for (int e = beg + lane; e < end; e += 64) {
            int s = csrc[e];
#pragma unroll
            for (int g = 0; g < H4; g++) {
                float4 as = *(const float4*)(al_s + (size_t)s * H + g * 4);
                m[g * 4 + 0] = fmaxf(m[g * 4 + 0], lrelu(as.x + ad[g * 4 + 0]));
                m[g * 4 + 1] = fmaxf(m[g * 4 + 1], lrelu(as.y + ad[g * 4 + 1]));
                m[g * 4 + 2] = fmaxf(m[g * 4 + 2], lrelu(as.z + ad[g * 4 + 2]));
                m[g * 4 + 3] = fmaxf(m[g * 4 + 3], lrelu(as.w + ad[g * 4 + 3]));
            }
        }
#pragma unroll
        for (int off = 32; off >= 1; off >>= 1)
#pragma unroll
            for (int j = 0; j < H; j++) m[j] = fmaxf(m[j], __shfl_xor(m[j], off));
#pragma unroll
        for (int j = 0; j < H; j++) sum[j] = 0.f;
        for (int e = beg + lane; e < end; e += 64) {
            int s = csrc[e];
#pragma unroll
            for (int g = 0; g < H4; g++) {
                float4 as = *(const float4*)(al_s + (size_t)s * H + g * 4);
                sum[g * 4 + 0] += __expf(lrelu(as.x + ad[g * 4 + 0]) - m[g * 4 + 0]);
                sum[g * 4 + 1] += __expf(lrelu(as.y + ad[g * 4 + 1]) - m[g * 4 + 1]);
                sum[g * 4 + 2] += __expf(lrelu(as.z + ad[g * 4 + 2]) - m[g * 4 + 2]);
                sum[g * 4 + 3] += __expf(lrelu(as.w + ad[g * 4 + 3]) - m[g * 4 + 3]);
            }
        }
#pragma unroll
        for (int off = 32; off >= 1; off >>= 1)
#pragma unroll
            for (int j = 0; j < H; j++) sum[j] += __shfl_xor(sum[j], off);
        float r[H];
#pragma unroll
        for (int j = 0; j < H; j++) r[j] = 1.0f / (sum[j] + 1e-16f);
        for (int base = beg; base < end; base += 64) {
            int cn = end - base < 64 ? end - base : 64;
            if (lane < cn) {
                int s = csrc[base + lane];
                lds_src[wv][lane] = s;
#pragma unroll
                for (int g = 0; g < H4; g++) {
                    float4 as = *(const float4*)(al_s + (size_t)s * H + g * 4);
                    float4 o;
                    o.x = __expf(lrelu(as.x + ad[g * 4 + 0]) - m[g * 4 + 0]) * r[g * 4 + 0];
                    o.y = __expf(lrelu(as.y + ad[g * 4 + 1]) - m[g * 4 + 1]) * r[g * 4 + 1];
                    o.z = __expf(lrelu(as.z + ad[g * 4 + 2]) - m[g * 4 + 2]) * r[g * 4 + 2];
                    o.w = __expf(lrelu(as.w + ad[g * 4 + 3]) - m[g * 4 + 3]) * r[g * 4 + 3];
                    *(float4*)&lds_alpha[wv][lane * H + g * 4] = o;
                }
            }
            for (int t = 0; t < cn; t++) {
                int s2 = lds_src[wv][t];
                _Float16 ah = (_Float16)lds_alpha[wv][t * H + hh];
                if constexpr (V == 8) {
                    half8 hv = *(const half8*)(h + (size_t)s2 * HC + ch);
                    half8 a2;
#pragma unroll
                    for (int i = 0; i < 8; i++) a2[i] = ah;
                    acc8 += hv * a2;
                } else {
                    half4 hv = *(const half4*)(h + (size_t)s2 * HC + ch);
                    half4 a2;
#pragma unroll
                    for (int i = 0; i < 4; i++) a2[i] = ah;
                    acc4 += hv * a2;
                }
            }
        }
    }

    float accf[V];
#pragma unroll
    for (int j = 0; j < V; j++)
        accf[j] = (V == 8) ? (float)acc8[j] : (float)acc4[j];

    if constexpr (MODE == 0) {
        unsigned short* out = (unsigned short*)out1v;
        unsigned short o[V];
#pragma unroll
        for (int j = 0; j < V; j++)
            o[j] = f2h(fmaxf(accf[j] + bias1[ch + j], 0.f));
        if constexpr (V == 8) {
            short8 ov;
#pragma unroll
            for (int j = 0; j < 8; j++) ov[j] = (short)o[j];
            *(short8*)(out + (size_t)n * HC + ch) = ov;
        } else {
            *(ushort4*)(out + (size_t)n * HC + ch) = make_ushort4(o[0], o[1], o[2], o[3]);
        }
    } else {
        // MODE 1: HC=256, V=4, 8 heads x 32ch -> mean over heads 0-3 / 4-7
        *(float4*)&shred[wv][ch] = make_float4(accf[0], accf[1], accf[2], accf[3]);
        if (lane < 32) {
            float v1 = (shred[wv][lane] + shred[wv][lane + 32] + shred[wv][lane + 64]
                        + shred[wv][lane + 96]) * 0.25f + bias1[lane];
            float v2 = (shred[wv][lane + 128] + shred[wv][lane + 160]
                        + shred[wv][lane + 192] + shred[wv][lane + 224]) * 0.25f
                       + bias2[lane];
            ((float*)out1v)[(size_t)n * 32 + lane] = v1;
            ((float*)out2v)[(size_t)n * 32 + lane] = v2;
        }
    }
}

// ---------------- orchestration ----------------

extern "C" void kernel_launch(void* const* d_in, const int* in_sizes, int n_in,
                              void* d_out, int out_size, void* d_ws, size_t ws_size,
                              hipStream_t stream) {
    (void)n_in; (void)out_size; (void)ws_size;
    const float* x   = (const float*)d_in[0];
    const int*   ei  = (const int*)d_in[1];
    const float* W1  = (const float*)d_in[2];
    const float* as1 = (const float*)d_in[3];
    const float* ad1 = (const float*)d_in[4];
    const float* b1  = (const float*)d_in[5];
    const float* W2  = (const float*)d_in[6];
    const float* as2 = (const float*)d_in[7];
    const float* ad2 = (const float*)d_in[8];
    const float* b2  = (const float*)d_in[9];
    const float* Wm  = (const float*)d_in[10];
    const float* a_sm = (const float*)d_in[11];
    const float* a_dm = (const float*)d_in[12];
    const float* bm  = (const float*)d_in[13];
    const float* Wl  = (const float*)d_in[14];
    const float* a_sl = (const float*)d_in[15];
    const float* a_dl = (const float*)d_in[16];
    const float* bl  = (const float*)d_in[17];
    float* outp = (float*)d_out;

    const int N  = in_sizes[0] / 256;   // 30000
    const int E  = in_sizes[1] / 2;     // 480000
    const int ET = E + N;               // with self loops
    const int gM128 = (N + 127) / 128;  // 235
    const int Mp = gM128 * 128;         // 30080 (padded rows; >= 469*64)
    const int gM64 = (N + 63) / 64;     // 469

    auto align_up = [](size_t v) { return (v + 255) & ~(size_t)255; };
    char* w = (char*)d_ws;
    int* row_ptr = (int*)w;  w += align_up((size_t)(N + 1) * 4);
    int* cnt     = (int*)w;  w += align_up((size_t)N * 4);
    int* csrc    = (int*)w;  w += align_up((size_t)ET * 4);
    float* al_s  = (float*)w; w += align_up((size_t)N * 8 * 4);
    float* al_d  = (float*)w; w += align_up((size_t)N * 8 * 4);
    unsigned short* xb   = (unsigned short*)w; w += align_up((size_t)Mp * 256 * 2);
    unsigned short* W1t  = (unsigned short*)w; w += align_up((size_t)256 * 256 * 2);
    unsigned short* W2t  = (unsigned short*)w; w += align_up((size_t)512 * 256 * 2);
    unsigned short* WmlT = (unsigned short*)w; w += align_up((size_t)256 * 512 * 2);
    unsigned short* bufH = (unsigned short*)w; w += align_up((size_t)Mp * 512 * 2);
    unsigned short* bufO = (unsigned short*)w; w += align_up((size_t)Mp * 512 * 2);

    // ---- CSR build ----
    int gzE = (ET + 255) / 256;
    hipMemsetAsync(cnt, 0, (size_t)N * 4, stream);
    count_edges_kernel<<<gzE, 256, 0, stream>>>(ei, E, N, cnt);
    scan_kernel<<<1, 1024, 0, stream>>>(cnt, row_ptr, N);   // re-zeroes cnt
    scatter_edges_kernel<<<gzE, 256, 0, stream>>>(ei, E, N, row_ptr, cnt, csrc);

    // ---- dtype prep ----
    f32_to_f16_pad4_kernel<<<((Mp * 256 / 4) + 255) / 256, 256, 0, stream>>>(
        x, xb, N, 256, Mp);
    transpose_all_kernel<<<(393216 + 255) / 256, 256, 0, stream>>>(
        W1, W2, Wm, Wl, W1t, W2t, WmlT);

    int gF = (N + 3) / 4;

    // ---- Layer 1: GAT(256 -> 4x64, concat) + ReLU ----
    gemm_f16_kernel<<<dim3(2, gM64), 256, 0, stream>>>(
        xb, W1t, bufH, N, 256, 256, al_s, al_d, as1, ad1, as1, ad1, 256, 64, 4);
    gat_fused_kernel<1, 4, 0><<<gF, 256, 0, stream>>>(
        row_ptr, csrc, al_s, al_d, bufH, b1, nullptr, bufO, nullptr, 256, 64, N);

    // ---- Layer 2: GAT(256 -> 4x128, concat) + ReLU ----
    gemm_f16_kernel<<<dim3(4, gM64), 256, 0, stream>>>(
        bufO, W2t, bufH, N, 256, 512, al_s, al_d, as2, ad2, as2, ad2, 512, 128, 4);
    gat_fused_kernel<1, 8, 0><<<gF, 256, 0, stream>>>(
        row_ptr, csrc, al_s, al_d, bufH, b2, nullptr, bufO, nullptr, 512, 128, N);

    // ---- Layers 3+4 batched: GAT(512 -> 8x32, mean per 4-head group) ----
    gemm_f16_kernel<<<dim3(2, gM64), 256, 0, stream>>>(
        bufO, WmlT, bufH, N, 512, 256, al_s, al_d, a_sm, a_dm, a_sl, a_dl, 128, 32, 8);
    gat_fused_kernel<2, 4, 1><<<gF, 256, 0, stream>>>(
        row_ptr, csrc, al_s, al_d, bufH, bm, bl, outp, outp + (size_t)N * 32, 256, 32, N);
}

// Round 12
// 441.365 us; speedup vs baseline: 1.2242x; 1.0121x over previous
//
#include <hip/hip_runtime.h>
#include <cstddef>

typedef __attribute__((ext_vector_type(8))) short short8;
typedef __attribute__((ext_vector_type(4))) float f32x4;
typedef __attribute__((ext_vector_type(8))) _Float16 half8;
typedef __attribute__((ext_vector_type(4))) _Float16 half4;

__device__ __forceinline__ unsigned short f2h(float f) {
    union { _Float16 h; unsigned short u; } x; x.h = (_Float16)f; return x.u;
}
__device__ __forceinline__ float lrelu(float v) { return v > 0.f ? v : 0.2f * v; }

// ---------------- CSR build ----------------

__global__ void count_edges_kernel(const int* __restrict__ ei, int E, int N,
                                   int* __restrict__ cnt) {
    int e = blockIdx.x * blockDim.x + threadIdx.x;
    if (e >= E + N) return;
    int d = (e < E) ? ei[E + e] : (e - E);  // self loops appended
    atomicAdd(&cnt[d], 1);
}

// single block, 1024 threads; also re-zeroes cnt for the scatter cursor.
__global__ void scan_kernel(int* __restrict__ cnt, int* __restrict__ rp, int n) {
    __shared__ int sh[1024];
    int t = threadIdx.x;
    int chunk = (n + 1023) >> 10;
    int beg = t * chunk;
    int end = beg + chunk < n ? beg + chunk : n;
    int local = 0;
    for (int i = beg; i < end; i++) local += cnt[i];
    sh[t] = local;
    __syncthreads();
    for (int off = 1; off < 1024; off <<= 1) {
        int v = (t >= off) ? sh[t - off] : 0;
        __syncthreads();
        sh[t] += v;
        __syncthreads();
    }
    int run = (t == 0) ? 0 : sh[t - 1];
    for (int i = beg; i < end; i++) {
        int c = cnt[i];
        cnt[i] = 0;
        run += c;
        rp[i + 1] = run;
    }
    if (t == 0) rp[0] = 0;
}

__global__ void scatter_edges_kernel(const int* __restrict__ ei, int E, int N,
                                     const int* __restrict__ rp, int* __restrict__ cur,
                                     int* __restrict__ csrc) {
    int e = blockIdx.x * blockDim.x + threadIdx.x;
    if (e >= E + N) return;
    int s, d;
    if (e < E) { s = ei[e]; d = ei[E + e]; } else { s = e - E; d = s; }
    int pos = rp[d] + atomicAdd(&cur[d], 1);
    csrc[pos] = s;
}

// ---------------- dtype prep ----------------

__global__ void f32_to_f16_pad4_kernel(const float* __restrict__ in,
                                       unsigned short* __restrict__ out,
                                       int rows, int cols, int padRows) {
    int i = blockIdx.x * blockDim.x + threadIdx.x;
    int total = (padRows * cols) >> 2;
    if (i >= total) return;
    int r = (i * 4) / cols;
    ushort4 o;
    if (r < rows) {
        float4 v = *(const float4*)(in + (size_t)i * 4);
        o = make_ushort4(f2h(v.x), f2h(v.y), f2h(v.z), f2h(v.w));
    } else {
        o = make_ushort4(0, 0, 0, 0);
    }
    *(ushort4*)(out + (size_t)i * 4) = o;
}

// All four weight transposes in one launch (f32 -> f16, [K,Nc] -> [Nc,K]).
__global__ void transpose_all_kernel(
    const float* __restrict__ W1, const float* __restrict__ W2,
    const float* __restrict__ Wm, const float* __restrict__ Wl,
    unsigned short* __restrict__ W1t, unsigned short* __restrict__ W2t,
    unsigned short* __restrict__ WmlT) {
    int i = blockIdx.x * blockDim.x + threadIdx.x;
    if (i < 65536) {
        int k = i >> 8, n = i & 255;
        W1t[(size_t)n * 256 + k] = f2h(W1[i]);
    } else if (i < 65536 + 131072) {
        int j = i - 65536;
        int k = j >> 9, n = j & 511;
        W2t[(size_t)n * 256 + k] = f2h(W2[j]);
    } else if (i < 65536 + 131072 + 65536) {
        int j = i - 196608;
        int k = j >> 7, n = j & 127;
        WmlT[(size_t)n * 512 + k] = f2h(Wm[j]);
    } else if (i < 65536 + 131072 + 131072) {
        int j = i - 262144;
        int k = j >> 7, n = j & 127;
        WmlT[(size_t)(128 + n) * 512 + k] = f2h(Wl[j]);
    }
}

// ---------------- f16 MFMA GEMM (software-pipelined) + al epilogue ----------------
// C[M,Nc] = A[Mp,K] @ Bt[Nc,K]^T; 64x128 tile, BK=32, 256 threads (2x2 waves of
// 32x64). K-loop software pipeline: next tile's global loads are issued right
// after this tile's LDS writes, BEFORE the MFMA burst -> load latency overlaps
// compute instead of stalling at the barrier.
// Epilogue: cols [bn,bn+128) contain complete heads; per-wave 16-lane reduce ->
// LDS -> 64 row-threads sum -> direct stores of al_s/al_d (no atomics).

__global__ __launch_bounds__(256) void gemm_f16_kernel(
    const unsigned short* __restrict__ A, const unsigned short* __restrict__ Bt,
    unsigned short* __restrict__ C, int M, int K, int Nc,
    float* __restrict__ al_s, float* __restrict__ al_d,
    const float* __restrict__ aslo, const float* __restrict__ adlo,
    const float* __restrict__ ashi, const float* __restrict__ adhi,
    int csplit, int Chead, int H) {
    __shared__ short As[64 * 32];
    __shared__ short Bs[128 * 32];
    __shared__ float salS[64][4];
    __shared__ float salD[64][4];
    int tid = threadIdx.x;
    int bm = blockIdx.y * 64;
    int bn = blockIdx.x * 128;
    int wave = tid >> 6, lane = tid & 63;
    int wm = (wave >> 1) * 32, wn = (wave & 1) * 64;
    int lm = lane & 15, lq = lane >> 4;

    f32x4 acc[2][4] = {};

    int c0 = tid, c1 = tid + 256;
    const unsigned short* Ap0 = A + (size_t)(bm + (c0 >> 2)) * K + (c0 & 3) * 8;
    const unsigned short* Bp0 = Bt + (size_t)(bn + (c0 >> 2)) * K + (c0 & 3) * 8;
    const unsigned short* Bp1 = Bt + (size_t)(bn + (c1 >> 2)) * K + (c1 & 3) * 8;

    short8 a0 = *(const short8*)(Ap0);
    short8 b0 = *(const short8*)(Bp0);
    short8 b1 = *(const short8*)(Bp1);

    for (int kk = 0; kk < K; kk += 32) {
        __syncthreads();           // prev iter's LDS frag reads done
        *(short8*)&As[c0 * 8] = a0;
        *(short8*)&Bs[c0 * 8] = b0;
        *(short8*)&Bs[c1 * 8] = b1;
        if (kk + 32 < K) {         // prefetch next tile BEFORE the MFMA burst
            a0 = *(const short8*)(Ap0 + kk + 32);
            b0 = *(const short8*)(Bp0 + kk + 32);
            b1 = *(const short8*)(Bp1 + kk + 32);
        }
        __syncthreads();           // this tile resident
        half8 af[2], bf[4];
#pragma unroll
        for (int t = 0; t < 2; t++)
            af[t] = *(const half8*)&As[(wm + t * 16 + lm) * 32 + lq * 8];
#pragma unroll
        for (int t = 0; t < 4; t++)
            bf[t] = *(const half8*)&Bs[(wn + t * 16 + lm) * 32 + lq * 8];
#pragma unroll
        for (int tm = 0; tm < 2; tm++)
#pragma unroll
            for (int tn = 0; tn < 4; tn++)
                acc[tm][tn] = __builtin_amdgcn_mfma_f32_16x16x32_f16(
                    af[tm], bf[tn], acc[tm][tn], 0, 0, 0);
    }

    // C store (f16)
#pragma unroll
    for (int tm = 0; tm < 2; tm++) {
#pragma unroll
        for (int r = 0; r < 4; r++) {
            int row = bm + wm + tm * 16 + lq * 4 + r;
            if (row < M) {
#pragma unroll
                for (int tn = 0; tn < 4; tn++) {
                    int col = bn + wn + tn * 16 + lm;
                    C[(size_t)row * Nc + col] = f2h(acc[tm][tn][r]);
                }
            }
        }
    }

    // attention-logit partial dots -> LDS (each (row, 32-col group) owned by
    // exactly one wave; no races)
    float asv[4], adv[4];
#pragma unroll
    for (int tn = 0; tn < 4; tn++) {
        int col = bn + wn + tn * 16 + lm;
        bool hi = col >= csplit;
        int cc = hi ? col - csplit : col;
        asv[tn] = hi ? ashi[cc] : aslo[cc];
        adv[tn] = hi ? adhi[cc] : adlo[cc];
    }
    int gb = wn >> 5;  // 0 or 2
#pragma unroll
    for (int tm = 0; tm < 2; tm++) {
#pragma unroll
        for (int r = 0; r < 4; r++) {
#pragma unroll
            for (int p = 0; p < 2; p++) {
                float s1 = acc[tm][2 * p][r] * asv[2 * p]
                         + acc[tm][2 * p + 1][r] * asv[2 * p + 1];
                float s2 = acc[tm][2 * p][r] * adv[2 * p]
                         + acc[tm][2 * p + 1][r] * adv[2 * p + 1];
#pragma unroll
                for (int off = 8; off >= 1; off >>= 1) {
                    s1 += __shfl_xor(s1, off);
                    s2 += __shfl_xor(s2, off);
                }
                if (lm == 0) {
                    int rl = wm + tm * 16 + lq * 4 + r;
                    salS[rl][gb + p] = s1;
                    salD[rl][gb + p] = s2;
                }
            }
        }
    }
    __syncthreads();
    if (tid < 64) {
        int row = bm + tid;
        if (row < M) {
            int hb = bn / Chead;       // first head in this col-block
            int HB = 128 / Chead;      // heads per col-block (1, 2, or 4)
            int GH = Chead >> 5;       // 32-col groups per head
            for (int i = 0; i < HB; i++) {
                float ss = 0.f, sd = 0.f;
                for (int j = 0; j < GH; j++) {
                    ss += salS[tid][i * GH + j];
                    sd += salD[tid][i * GH + j];
                }
                al_s[(size_t)row * H + hb + i] = ss;
                al_d[(size_t)row * H + hb + i] = sd;
            }
        }
    }
}

// ---------------- fused per-node softmax + aggregate, 4 nodes/block ----------------
// 4 waves/block, each wave owns one dst node. Lane-per-edge softmax via
// butterfly shuffles; alpha parked in LDS; gather-aggregate with PACKED F16
// FMAs (V channels/lane), 8-edge unroll.
// MODE 0: concat + bias + ReLU, f16 out. MODE 1: 8 heads x 32ch -> head-mean
// over groups 0-3 / 4-7 + bias, f32 out1/out2.

template <int H4, int V, int MODE>
__global__ __launch_bounds__(256) void gat_fused_kernel(
    const int* __restrict__ rp, const int* __restrict__ csrc,
    const float* __restrict__ al_s, const float* __restrict__ al_d,
    const unsigned short* __restrict__ h,
    const float* __restrict__ bias1, const float* __restrict__ bias2,
    void* __restrict__ out1v, void* __restrict__ out2v, int HC, int C, int N) {
    const int H = 4 * H4;
    __shared__ int lds_src[4][64];
    __shared__ float lds_alpha[4][64 * 4 * H4];
    __shared__ float shred[4][256];
    int wv = threadIdx.x >> 6;
    int lane = threadIdx.x & 63;
    int n = blockIdx.x * 4 + wv;
    if (n >= N) return;
    int beg = rp[n], end = rp[n + 1];
    int deg = end - beg;

    float ad[H];
#pragma unroll
    for (int g = 0; g < H4; g++)
        *(float4*)&ad[g * 4] = *(const float4*)(al_d + (size_t)n * H + g * 4);

    int ch = lane * V;
    int hh = ch / C;
    half8 acc8 = {};
    half4 acc4 = {};

    if (deg <= 64) {
        bool act = lane < deg;
        int s = act ? csrc[beg + lane] : 0;
        float v[H], m[H], ex[H], sum[H];
#pragma unroll
        for (int g = 0; g < H4; g++) {
            float4 as = *(const float4*)(al_s + (size_t)s * H + g * 4);
            v[g * 4 + 0] = lrelu(as.x + ad[g * 4 + 0]);
            v[g * 4 + 1] = lrelu(as.y + ad[g * 4 + 1]);
            v[g * 4 + 2] = lrelu(as.z + ad[g * 4 + 2]);
            v[g * 4 + 3] = lrelu(as.w + ad[g * 4 + 3]);
        }
#pragma unroll
        for (int j = 0; j < H; j++) m[j] = act ? v[j] : -3.402823466e38f;
#pragma unroll
        for (int off = 32; off >= 1; off >>= 1)
#pragma unroll
            for (int j = 0; j < H; j++) m[j] = fmaxf(m[j], __shfl_xor(m[j], off));
#pragma unroll
        for (int j = 0; j < H; j++) {
            ex[j] = act ? __expf(v[j] - m[j]) : 0.f;
            sum[j] = ex[j];
        }
#pragma unroll
        for (int off = 32; off >= 1; off >>= 1)
#pragma unroll
            for (int j = 0; j < H; j++) sum[j] += __shfl_xor(sum[j], off);
        if (act) {
            lds_src[wv][lane] = s;
#pragma unroll
            for (int g = 0; g < H4; g++) {
                float4 o;
                o.x = ex[g * 4 + 0] / (sum[g * 4 + 0] + 1e-16f);
                o.y = ex[g * 4 + 1] / (sum[g * 4 + 1] + 1e-16f);
                o.z = ex[g * 4 + 2] / (sum[g * 4 + 2] + 1e-16f);
                o.w = ex[g * 4 + 3] / (sum[g * 4 + 3] + 1e-16f);
                *(float4*)&lds_alpha[wv][lane * H + g * 4] = o;
            }
        }
        // wave-local LDS write->read (lockstep wave, compiler lgkmcnt ordering)
        int t = 0;
        for (; t + 8 <= deg; t += 8) {
            int ss[8]; float av[8];
#pragma unroll
            for (int u = 0; u < 8; u++) {
                ss[u] = lds_src[wv][t + u];
                av[u] = lds_alpha[wv][(t + u) * H + hh];
            }
            if constexpr (V == 8) {
                half8 hv[8];
#pragma unroll
                for (int u = 0; u < 8; u++)
                    hv[u] = *(const half8*)(h + (size_t)ss[u] * HC + ch);
#pragma unroll
                for (int u = 0; u < 8; u++) {
                    _Float16 ah = (_Float16)av[u];
                    half8 a2;
#pragma unroll
                    for (int i = 0; i < 8; i++) a2[i] = ah;
                    acc8 += hv[u] * a2;
                }
            } else {
                half4 hv[8];
#pragma unroll
                for (int u = 0; u < 8; u++)
                    hv[u] = *(const half4*)(h + (size_t)ss[u] * HC + ch);
#pragma unroll
                for (int u = 0; u < 8; u++) {
                    _Float16 ah = (_Float16)av[u];
                    half4 a2;
#pragma unroll
                    for (int i = 0; i < 4; i++) a2[i] = ah;
                    acc4 += hv[u] * a2;
                }
            }
        }
        for (; t < deg; t++) {
            int s2 = lds_src[wv][t];
            _Float16 ah = (_Float16)lds_alpha[wv][t * H + hh];
            if constexpr (V == 8) {
                half8 hv = *(const half8*)(h + (size_t)s2 * HC + ch);
                half8 a2;
#pragma unroll
                for (int i = 0; i < 8; i++) a2[i] = ah;
                acc8 += hv * a2;
            } else {
                half4 hv = *(const half4*)(h + (size_t)s2 * HC + ch);
                half4 a2;
#pragma unroll
                for (int i = 0; i < 4; i++) a2[i] = ah;
                acc4 += hv * a2;
            }
        }
    } else {
        // general path (deg > 64): strided stats with recompute, chunked agg
        float m[H], sum[H];
#pragma unroll
        for (int j = 0; j < H; j++) m[j] = -3.402823466e38f;
        for (int e = beg + lane; e < end; e += 64) {
            int s = csrc[e];
#pragma unroll
            for (int g = 0; g < H4; g++) {
                float4 as = *(const float4*)(al_s + (size_t)s * H + g * 4);
                m[g * 4 + 0] = fmaxf(m[g * 4 + 0], lrelu(as.x + ad[g * 4 + 0]));
                m[g * 4 + 1] = fmaxf(m[g * 4 + 1], lrelu(as.y + ad[g * 4 + 1]));
                m[g * 4 + 2] = fmaxf(m[g * 4 + 2], lrelu(as.z + ad[g * 4 + 2]));
                m[g * 4 + 3] = fmaxf(m[g * 4 + 3], lrelu(as.w + ad[g * 4 + 3]));
            }
        }
#pragma unroll
        for (int off = 32; off >= 1; off >>= 1)
#pragma unroll
            for (int j = 0; j < H; j++) m[j] = fmaxf(m[j], __shfl_xor(m[j], off));
#pragma unroll
        for (int j = 0; j < H; j++) sum[j] = 0.f;
        for (int e = beg + lane; e < end; e += 64) {
            int s = csrc[e];
#pragma unroll
            for (int g = 0; g < H4; g++) {
                float4 as = *(const float4*)(al_s + (size_t)s * H + g * 4);
                sum[g * 4 + 0] += __expf(lrelu(as.x + ad[g * 4 + 0]) - m[g * 4 + 0]);
                sum[g * 4 + 1] += __expf(lrelu(as.y + ad[g * 4 + 1]) - m[g * 4 + 1]);
                sum[g * 4 + 2] += __expf(lrelu(as.z + ad[g * 4 + 2]) - m[g * 4 + 2]);
                sum[g * 4 + 3] += __expf(lrelu(as.w + ad[g * 4 + 3]) - m[g * 4 + 3]);
            }
        }
#pragma unroll
        for (int off = 32; off >= 1; off >>= 1)
#pragma unroll
            for (int j = 0; j < H; j++) sum[j] += __shfl_xor(sum[j], off);
        float r[H];
#pragma unroll
        for (int j = 0; j < H; j++) r[j] = 1.0f / (sum[j] + 1e-16f);
        for (int base = beg; base < end; base += 64) {
            int cn = end - base < 64 ? end - base : 64;
            if (lane < cn) {
                int s = csrc[base + lane];
                lds_src[wv][lane] = s;
#pragma unroll
                for (int g = 0; g < H4; g++) {
                    float4 as = *(const float4*)(al_s + (size_t)s * H + g * 4);
                    float4 o;
                    o.x = __expf(lrelu(as.x + ad[g * 4 + 0]) - m[g * 4 + 0]) * r[g * 4 + 0];
                    o.y = __expf(lrelu(as.y + ad[g * 4 + 1]) - m[g * 4 + 1]) * r[g * 4 + 1];
                    o.z = __expf(lrelu(as.z + ad[g * 4 + 2]) - m[g * 4 + 2]) * r[g * 4 + 2];
                    o.w = __expf(lrelu(as.w + ad[g * 4 + 3]) - m[g * 4 + 3]) * r[g * 4 + 3];
                    *(float4*)&lds_alpha[wv][lane * H + g * 4] = o;
                }
            }
            for (int t = 0; t < cn; t++) {
                int s2 = lds_src[wv][t];
                _Float16 ah = (_Float16)lds_alpha[wv][t * H + hh];
                if constexpr (V == 8) {
                    half8 hv = *(const half8*)(h + (size_t)s2 * HC + ch);
                    half8 a2;
#pragma unroll
                    for (int i = 0; i < 8; i++) a2[i] = ah;
                    acc8 += hv * a2;
                } else {
                    half4 hv = *(const half4*)(h + (size_t)s2 * HC + ch);
                    half4 a2;
#pragma unroll
                    for (int i = 0; i < 4; i++) a2[i] = ah;
                    acc4 += hv * a2;
                }
            }
        }
    }

    float accf[V];
#pragma unroll
    for (int j = 0; j < V; j++)
        accf[j] = (V == 8) ? (float)acc8[j] : (float)acc4[j];

    if constexpr (MODE == 0) {
        unsigned short* out = (unsigned short*)out1v;
        unsigned short o[V];
#pragma unroll
        for (int j = 0; j < V; j++)
            o[j] = f2h(fmaxf(accf[j] + bias1[ch + j], 0.f));
        if constexpr (V == 8) {
            short8 ov;
#pragma unroll
            for (int j = 0; j < 8; j++) ov[j] = (short)o[j];
            *(short8*)(out + (size_t)n * HC + ch) = ov;
        } else {
            *(ushort4*)(out + (size_t)n * HC + ch) = make_ushort4(o[0], o[1], o[2], o[3]);
        }
    } else {
        // MODE 1: HC=256, V=4, 8 heads x 32ch -> mean over heads 0-3 / 4-7
        *(float4*)&shred[wv][ch] = make_float4(accf[0], accf[1], accf[2], accf[3]);
        if (lane < 32) {
            float v1 = (shred[wv][lane] + shred[wv][lane + 32] + shred[wv][lane + 64]
                        + shred[wv][lane + 96]) * 0.25f + bias1[lane];
            float v2 = (shred[wv][lane + 128] + shred[wv][lane + 160]
                        + shred[wv][lane + 192] + shred[wv][lane + 224]) * 0.25f
                       + bias2[lane];
            ((float*)out1v)[(size_t)n * 32 + lane] = v1;
            ((float*)out2v)[(size_t)n * 32 + lane] = v2;
        }
    }
}

// ---------------- orchestration ----------------

extern "C" void kernel_launch(void* const* d_in, const int* in_sizes, int n_in,
                              void* d_out, int out_size, void* d_ws, size_t ws_size,
                              hipStream_t stream) {
    (void)n_in; (void)out_size; (void)ws_size;
    const float* x   = (const float*)d_in[0];
    const int*   ei  = (const int*)d_in[1];
    const float* W1  = (const float*)d_in[2];
    const float* as1 = (const float*)d_in[3];
    const float* ad1 = (const float*)d_in[4];
    const float* b1  = (const float*)d_in[5];
    const float* W2  = (const float*)d_in[6];
    const float* as2 = (const float*)d_in[7];
    const float* ad2 = (const float*)d_in[8];
    const float* b2  = (const float*)d_in[9];
    const float* Wm  = (const float*)d_in[10];
    const float* a_sm = (const float*)d_in[11];
    const float* a_dm = (const float*)d_in[12];
    const float* bm  = (const float*)d_in[13];
    const float* Wl  = (const float*)d_in[14];
    const float* a_sl = (const float*)d_in[15];
    const float* a_dl = (const float*)d_in[16];
    const float* bl  = (const float*)d_in[17];
    float* outp = (float*)d_out;

    const int N  = in_sizes[0] / 256;   // 30000
    const int E  = in_sizes[1] / 2;     // 480000
    const int ET = E + N;               // with self loops
    const int gM128 = (N + 127) / 128;  // 235
    const int Mp = gM128 * 128;         // 30080 (padded rows; >= 469*64)
    const int gM64 = (N + 63) / 64;     // 469

    auto align_up = [](size_t v) { return (v + 255) & ~(size_t)255; };
    char* w = (char*)d_ws;
    int* row_ptr = (int*)w;  w += align_up((size_t)(N + 1) * 4);
    int* cnt     = (int*)w;  w += align_up((size_t)N * 4);
    int* csrc    = (int*)w;  w += align_up((size_t)ET * 4);
    float* al_s  = (float*)w; w += align_up((size_t)N * 8 * 4);
    float* al_d  = (float*)w; w += align_up((size_t)N * 8 * 4);
    unsigned short* xb   = (unsigned short*)w; w += align_up((size_t)Mp * 256 * 2);
    unsigned short* W1t  = (unsigned short*)w; w += align_up((size_t)256 * 256 * 2);
    unsigned short* W2t  = (unsigned short*)w; w += align_up((size_t)512 * 256 * 2);
    unsigned short* WmlT = (unsigned short*)w; w += align_up((size_t)256 * 512 * 2);
    unsigned short* bufH = (unsigned short*)w; w += align_up((size_t)Mp * 512 * 2);
    unsigned short* bufO = (unsigned short*)w; w += align_up((size_t)Mp * 512 * 2);

    // ---- CSR build ----
    int gzE = (ET + 255) / 256;
    hipMemsetAsync(cnt, 0, (size_t)N * 4, stream);
    count_edges_kernel<<<gzE, 256, 0, stream>>>(ei, E, N, cnt);
    scan_kernel<<<1, 1024, 0, stream>>>(cnt, row_ptr, N);   // re-zeroes cnt
    scatter_edges_kernel<<<gzE, 256, 0, stream>>>(ei, E, N, row_ptr, cnt, csrc);

    // ---- dtype prep ----
    f32_to_f16_pad4_kernel<<<((Mp * 256 / 4) + 255) / 256, 256, 0, stream>>>(
        x, xb, N, 256, Mp);
    transpose_all_kernel<<<(393216 + 255) / 256, 256, 0, stream>>>(
        W1, W2, Wm, Wl, W1t, W2t, WmlT);

    int gF = (N + 3) / 4;

    // ---- Layer 1: GAT(256 -> 4x64, concat) + ReLU ----
    gemm_f16_kernel<<<dim3(2, gM64), 256, 0, stream>>>(
        xb, W1t, bufH, N, 256, 256, al_s, al_d, as1, ad1, as1, ad1, 256, 64, 4);
    gat_fused_kernel<1, 4, 0><<<gF, 256, 0, stream>>>(
        row_ptr, csrc, al_s, al_d, bufH, b1, nullptr, bufO, nullptr, 256, 64, N);

    // ---- Layer 2: GAT(256 -> 4x128, concat) + ReLU ----
    gemm_f16_kernel<<<dim3(4, gM64), 256, 0, stream>>>(
        bufO, W2t, bufH, N, 256, 512, al_s, al_d, as2, ad2, as2, ad2, 512, 128, 4);
    gat_fused_kernel<1, 8, 0><<<gF, 256, 0, stream>>>(
        row_ptr, csrc, al_s, al_d, bufH, b2, nullptr, bufO, nullptr, 512, 128, N);

    // ---- Layers 3+4 batched: GAT(512 -> 8x32, mean per 4-head group) ----
    gemm_f16_kernel<<<dim3(2, gM64), 256, 0, stream>>>(
        bufO, WmlT, bufH, N, 512, 256, al_s, al_d, a_sm, a_dm, a_sl, a_dl, 128, 32, 8);
    gat_fused_kernel<2, 4, 1><<<gF, 256, 0, stream>>>(
        row_ptr, csrc, al_s, al_d, bufH, bm, bl, outp, outp + (size_t)N * 32, 256, 32, N);
}